// Round 2
// 148.295 us; speedup vs baseline: 1.0369x; 1.0369x over previous
//
#include <hip/hip_runtime.h>
#include <hip/hip_bf16.h>

// (B,S,H,D) = (2,2048,16,64), fp32 in/out, int32 mask (True -> -inf).
#define BB 2
#define SS 2048
#define HH 16
#define DD 64
#define BR 128         // query rows per block (4 waves x 32)
#define BC 64          // keys per inner tile
#define NT (SS / BC)   // 32 key tiles
#define NQT (SS / BR)  // 16 query tiles
#define TILE_E (BC * DD)        // 4096 bf16 elems = 8 KB per tile
#define LOG2E 1.44269504f
#define LSTR 72        // prep LDS transpose row stride (ushort)
#define OSZ (BB * SS * HH * DD)   // 4M output elems

typedef __attribute__((ext_vector_type(8))) short short8;
typedef __attribute__((ext_vector_type(4))) float f32x4;
typedef __attribute__((ext_vector_type(16))) float f32x16;
typedef __attribute__((ext_vector_type(4))) unsigned int uint32x4;
typedef __attribute__((ext_vector_type(4))) unsigned short ushort4_t;

// fp32 -> bf16 RNE (scalar fallback / prep V path)
static __device__ __forceinline__ unsigned short f2bf(float f) {
    unsigned int u = __float_as_uint(f);
    unsigned int r = u + 0x7FFFu + ((u >> 16) & 1u);
    return (unsigned short)(r >> 16);
}
// fp32 pair -> packed bf16x2 via single v_cvt_pk_bf16_f32 (RNE, same bits as f2bf)
static __device__ __forceinline__ unsigned int cvtpk(float lo, float hi) {
    unsigned int r;
    asm("v_cvt_pk_bf16_f32 %0, %1, %2" : "=v"(r) : "v"(lo), "v"(hi));
    return r;
}
// swap upper 32 lanes of a with lower 32 lanes of b (one VALU op, no LDS pipe)
static __device__ __forceinline__ void pl32swap(unsigned int &a, unsigned int &b) {
#if __has_builtin(__builtin_amdgcn_permlane32_swap)
    const auto r = __builtin_amdgcn_permlane32_swap((int)a, (int)b, false, false);
    a = (unsigned int)r[0];
    b = (unsigned int)r[1];
#else
    asm("v_permlane32_swap_b32 %0, %1" : "+v"(a), "+v"(b));
#endif
}
static __device__ __forceinline__ float fexp2(float x) {
#if __has_builtin(__builtin_amdgcn_exp2f)
    return __builtin_amdgcn_exp2f(x);
#else
    return exp2f(x);
#endif
}
// async global->LDS, 16B per lane
static __device__ __forceinline__ void gl_lds16(const void* g, void* l) {
    __builtin_amdgcn_global_load_lds(
        (const __attribute__((address_space(1))) void*)g,
        (__attribute__((address_space(3))) void*)l, 16, 0, 0);
}

// ---------------------------------------------------------------------------
// Pre-pass: K -> bf16 swizzled tiles with MASKED ROWS ZEROED, V -> bf16
// transposed tiles with masked rows zeroed, per-tile masked-key counts.
// Masked key k: K row 0 -> s=0 -> p=exp2(0)=1; V row 0 -> PV contrib 0;
// l corrected by subtracting the (integer) masked count. Exact.
// Tile layout (LDS-linear 8KB): elem offset r*64 + ((c ^ (r&7))*8) + j.
// ---------------------------------------------------------------------------
__global__ __launch_bounds__(256, 2)
void prep_kernel(const float* __restrict__ K, const float* __restrict__ V,
                 const int* __restrict__ M,
                 unsigned short* __restrict__ Kb, unsigned short* __restrict__ Vt,
                 int* __restrict__ mcnt)
{
    __shared__ unsigned short Vl[DD * LSTR];

    const int t  = blockIdx.x & (NT - 1);
    const int b  = blockIdx.x >> 9;
    const int bh = blockIdx.x >> 5;
    const int tid = threadIdx.x;
    const size_t tile = (size_t)blockIdx.x * TILE_E;
    const size_t rs = (size_t)HH * DD;
    const float* kb0 = K + (((size_t)b * SS + t * BC) * HH + (bh & 15)) * DD;
    const float* vb0 = V + (((size_t)b * SS + t * BC) * HH + (bh & 15)) * DD;
    const int* mrow = M + (size_t)b * SS + t * BC;

    // ---- K: coalesced read, zero masked rows, swizzled coalesced write ----
    {
        const int p  = tid & 7;
        const int r0 = tid >> 3;
        #pragma unroll
        for (int half = 0; half < 2; ++half) {
            const int r = r0 + half * 32;
            const int c = p ^ (r & 7);
            const float sel = mrow[r] ? 0.0f : 1.0f;
            const float* ks = kb0 + (size_t)r * rs + c * 8;
            const float4 f0 = *(const float4*)ks;
            const float4 f1 = *(const float4*)(ks + 4);
            uint32x4 u;
            u[0] = cvtpk(f0.x * sel, f0.y * sel);
            u[1] = cvtpk(f0.z * sel, f0.w * sel);
            u[2] = cvtpk(f1.x * sel, f1.y * sel);
            u[3] = cvtpk(f1.z * sel, f1.w * sel);
            *(uint32x4*)(Kb + tile + r * 64 + p * 8) = u;
        }
    }
    // ---- V: coalesced read, zero masked rows, LDS transpose, write ----
    {
        const int vr = tid >> 2;
        const int vc = tid & 3;
        const float sel = mrow[vr] ? 0.0f : 1.0f;
        const float* vp = vb0 + (size_t)vr * rs + vc * 16;
        #pragma unroll
        for (int i = 0; i < 4; ++i) {
            const float4 f = *(const float4*)(vp + i * 4);
            const int d = vc * 16 + i * 4;
            Vl[(d + 0) * LSTR + vr] = f2bf(f.x * sel);
            Vl[(d + 1) * LSTR + vr] = f2bf(f.y * sel);
            Vl[(d + 2) * LSTR + vr] = f2bf(f.z * sel);
            Vl[(d + 3) * LSTR + vr] = f2bf(f.w * sel);
        }
    }
    __syncthreads();
    {
        const int p  = tid & 7;
        const int r0 = tid >> 3;
        #pragma unroll
        for (int half = 0; half < 2; ++half) {
            const int r = r0 + half * 32;
            const int c = p ^ (r & 7);
            const short8 o = *(const short8*)&Vl[r * LSTR + c * 8];
            *(short8*)(Vt + tile + r * 64 + p * 8) = o;
        }
    }
    // ---- masked-key count for this tile ----
    if ((bh & 15) == 0 && tid < 64) {
        const unsigned long long bal = __ballot(mrow[tid] != 0);
        if (tid == 0) mcnt[b * NT + t] = (int)__popcll(bal);
    }
}

// ---------------------------------------------------------------------------
// Flash kernel: 32x32x16 MFMA, S^T formulation, P redistribution via
// v_cvt_pk_bf16_f32 + v_permlane32_swap_b32 (T12), mask pre-baked into K/V,
// double-buffered staging. SPLIT: 2-way key split with unnormalized partials
// + l sums to workspace.
// ---------------------------------------------------------------------------
template<bool SPLIT>
__global__ __launch_bounds__(256, 2)
void fa3_kernel(const float* __restrict__ Q,
                const unsigned short* __restrict__ Kb,
                const unsigned short* __restrict__ Vt,
                const int* __restrict__ mcnt,
                float* __restrict__ Op,      // SPLIT: partials; else final O
                float* __restrict__ Lp)      // SPLIT: l partials; else unused
{
    __shared__ __align__(16) unsigned short Ks[2][TILE_E];
    __shared__ __align__(16) unsigned short Vs[2][TILE_E];

    const int blk = blockIdx.x;
    const int qt  = blk & (NQT - 1);
    const int bh  = (blk >> 4) & 31;
    const int spl = SPLIT ? (blk >> 9) : 0;
    const int b   = bh >> 4;
    const int h   = bh & 15;
    const int kt0 = SPLIT ? spl * (NT / 2) : 0;
    const int ktn = SPLIT ? (NT / 2) : NT;

    const int tid  = threadIdx.x;
    const int wave = tid >> 6;
    const int lane = tid & 63;
    const int ln   = lane & 31;
    const int l5   = lane >> 5;

    // ---- Q fragments: B-operand B[k=d][n=q], n=ln, k=l5*8+j per d-step ----
    const float qscale = 0.125f * LOG2E;
    const int qrow = qt * BR + wave * 32 + ln;
    const float* qp = Q + (((size_t)b * SS + qrow) * HH + h) * DD;
    short8 qf[4];
    #pragma unroll
    for (int t = 0; t < 4; ++t) {
        const int d0 = t * 16 + l5 * 8;
        const float4 f0 = *(const float4*)(qp + d0);
        const float4 f1 = *(const float4*)(qp + d0 + 4);
        uint32x4 u;
        u[0] = cvtpk(f0.x * qscale, f0.y * qscale);
        u[1] = cvtpk(f0.z * qscale, f0.w * qscale);
        u[2] = cvtpk(f1.x * qscale, f1.y * qscale);
        u[3] = cvtpk(f1.z * qscale, f1.w * qscale);
        qf[t] = __builtin_bit_cast(short8, u);
    }

    // masked-key correction for this block's key range (uniform scalar loads)
    int corr = 0;
    for (int i = 0; i < ktn; ++i) corr += mcnt[b * NT + kt0 + i];

    f32x16 acc0, acc1;
    #pragma unroll
    for (int i = 0; i < 16; ++i) { acc0[i] = 0.f; acc1[i] = 0.f; }
    f32x4 lsum4 = {0.f, 0.f, 0.f, 0.f};

    const unsigned short* kb_bh = Kb + (size_t)bh * NT * TILE_E;
    const unsigned short* vt_bh = Vt + (size_t)bh * NT * TILE_E;
    const int we = wave * 1024;
    const int wb = wave * 2048;

    // ---- prologue: stage first tile into buffer 0 ----
    {
        const unsigned short* kbt = kb_bh + (size_t)kt0 * TILE_E;
        const unsigned short* vtt = vt_bh + (size_t)kt0 * TILE_E;
        gl_lds16(kbt + we + lane * 8,       (char*)Ks[0] + wb);
        gl_lds16(kbt + we + 512 + lane * 8, (char*)Ks[0] + wb + 1024);
        gl_lds16(vtt + we + lane * 8,       (char*)Vs[0] + wb);
        gl_lds16(vtt + we + 512 + lane * 8, (char*)Vs[0] + wb + 1024);
    }
    __syncthreads();

    const int pswz = (ln & 7);

    for (int it = 0; it < ktn; ++it) {
        const int cur = it & 1;
        const int nxt = cur ^ 1;
        const int kn = kt0 + ((it + 1 < ktn) ? it + 1 : it);
        const unsigned short* kbt = kb_bh + (size_t)kn * TILE_E;
        const unsigned short* vtt = vt_bh + (size_t)kn * TILE_E;
        gl_lds16(kbt + we + lane * 8,       (char*)Ks[nxt] + wb);
        gl_lds16(kbt + we + 512 + lane * 8, (char*)Ks[nxt] + wb + 1024);
        gl_lds16(vtt + we + lane * 8,       (char*)Vs[nxt] + wb);
        gl_lds16(vtt + we + 512 + lane * 8, (char*)Vs[nxt] + wb + 1024);

        // ---- S^T = K Q^T ----
        f32x16 s0, s1;
        #pragma unroll
        for (int i = 0; i < 16; ++i) { s0[i] = 0.f; s1[i] = 0.f; }
        #pragma unroll
        for (int t = 0; t < 4; ++t) {
            const int p = (2 * t + l5) ^ pswz;
            const short8 kf0 = *(const short8*)(Ks[cur] + ln * 64 + p * 8);
            const short8 kf1 = *(const short8*)(Ks[cur] + (32 + ln) * 64 + p * 8);
            s0 = __builtin_amdgcn_mfma_f32_32x32x16_bf16(kf0, qf[t], s0, 0, 0, 0);
            s1 = __builtin_amdgcn_mfma_f32_32x32x16_bf16(kf1, qf[t], s1, 0, 0, 0);
        }

        // ---- exp2 + lsum (v_pk_add_f32) + pack (v_cvt_pk_bf16_f32) ----
        unsigned int pk[2][8];
        #pragma unroll
        for (int hh = 0; hh < 2; ++hh) {
            #pragma unroll
            for (int g = 0; g < 4; ++g) {
                const float p0 = fexp2(hh ? s1[g * 4 + 0] : s0[g * 4 + 0]);
                const float p1 = fexp2(hh ? s1[g * 4 + 1] : s0[g * 4 + 1]);
                const float p2 = fexp2(hh ? s1[g * 4 + 2] : s0[g * 4 + 2]);
                const float p3 = fexp2(hh ? s1[g * 4 + 3] : s0[g * 4 + 3]);
                lsum4 += (f32x4){p0, p1, p2, p3};
                pk[hh][g * 2 + 0] = cvtpk(p0, p1);
                pk[hh][g * 2 + 1] = cvtpk(p2, p3);
            }
        }
        // ---- cross-half redistribution: 8 permlane32_swap, no LDS pipe ----
        // swap(pk[2g0], pk[2g1]) gives exactly the old l5-select of {pk,xk}:
        // lanes<32 keep rows g0*8+{0,1} / get partner rows g0*8+{4,5};
        // lanes>=32 get rows g1*8+{0,1} / keep rows g1*8+{12,13}.
        #pragma unroll
        for (int hh = 0; hh < 2; ++hh) {
            pl32swap(pk[hh][0], pk[hh][2]);
            pl32swap(pk[hh][1], pk[hh][3]);
            pl32swap(pk[hh][4], pk[hh][6]);
            pl32swap(pk[hh][5], pk[hh][7]);
        }
        short8 pf[4];
        #pragma unroll
        for (int t = 0; t < 4; ++t) {
            const int hh = t >> 1;
            const int s4 = (t & 1) * 4;
            uint32x4 u;
            u[0] = pk[hh][s4 + 0];
            u[1] = pk[hh][s4 + 1];
            u[2] = pk[hh][s4 + 2];
            u[3] = pk[hh][s4 + 3];
            pf[t] = __builtin_bit_cast(short8, u);
        }

        // ---- O^T += V^T P^T ----
        #pragma unroll
        for (int t = 0; t < 4; ++t) {
            const int p = (2 * t + l5) ^ pswz;
            const short8 vf0 = *(const short8*)(Vs[cur] + ln * 64 + p * 8);
            const short8 vf1 = *(const short8*)(Vs[cur] + (32 + ln) * 64 + p * 8);
            acc0 = __builtin_amdgcn_mfma_f32_32x32x16_bf16(vf0, pf[t], acc0, 0, 0, 0);
            acc1 = __builtin_amdgcn_mfma_f32_32x32x16_bf16(vf1, pf[t], acc1, 0, 0, 0);
        }

        __syncthreads();
    }

    // ---- epilogue ----
    const float lsum = (lsum4[0] + lsum4[1]) + (lsum4[2] + lsum4[3]);
    const float l = lsum + __shfl_xor(lsum, 32) - (float)corr;
    if (SPLIT) {
        float* op = Op + (size_t)spl * OSZ + (((size_t)b * SS + qrow) * HH + h) * DD;
        #pragma unroll
        for (int dh = 0; dh < 2; ++dh) {
            #pragma unroll
            for (int g = 0; g < 4; ++g) {
                const int d0 = dh * 32 + 8 * g + 4 * l5;
                float4 o;
                o.x = dh ? acc1[g * 4 + 0] : acc0[g * 4 + 0];
                o.y = dh ? acc1[g * 4 + 1] : acc0[g * 4 + 1];
                o.z = dh ? acc1[g * 4 + 2] : acc0[g * 4 + 2];
                o.w = dh ? acc1[g * 4 + 3] : acc0[g * 4 + 3];
                *(float4*)(op + d0) = o;
            }
        }
        if (l5 == 0)
            Lp[spl * (BB * HH * SS) + (b * HH + h) * SS + qrow] = l;
    } else {
        const float inv = 1.0f / l;
        float* op = Op + (((size_t)b * SS + qrow) * HH + h) * DD;
        #pragma unroll
        for (int dh = 0; dh < 2; ++dh) {
            #pragma unroll
            for (int g = 0; g < 4; ++g) {
                const int d0 = dh * 32 + 8 * g + 4 * l5;
                float4 o;
                o.x = (dh ? acc1[g * 4 + 0] : acc0[g * 4 + 0]) * inv;
                o.y = (dh ? acc1[g * 4 + 1] : acc0[g * 4 + 1]) * inv;
                o.z = (dh ? acc1[g * 4 + 2] : acc0[g * 4 + 2]) * inv;
                o.w = (dh ? acc1[g * 4 + 3] : acc0[g * 4 + 3]) * inv;
                *(float4*)(op + d0) = o;
            }
        }
    }
}

// ---------------------------------------------------------------------------
// Combine: O = (Ou0 + Ou1) / (l0 + l1), float4 per thread.
// ---------------------------------------------------------------------------
__global__ __launch_bounds__(256, 4)
void combine_kernel(const float* __restrict__ Ou, const float* __restrict__ Lp,
                    float* __restrict__ O)
{
    const int gid = blockIdx.x * 256 + threadIdx.x;
    const int i = gid * 4;
    const int b   = i >> 21;             // S*H*D = 2^21
    const int row = (i >> 10) & (SS - 1);
    const int h   = (i >> 6) & (HH - 1);
    const int li  = (b * HH + h) * SS + row;
    const float l = Lp[li] + Lp[BB * HH * SS + li];
    const float inv = 1.0f / l;
    const float4 a = *(const float4*)(Ou + i);
    const float4 c = *(const float4*)(Ou + OSZ + i);
    float4 o;
    o.x = (a.x + c.x) * inv;
    o.y = (a.y + c.y) * inv;
    o.z = (a.z + c.z) * inv;
    o.w = (a.w + c.w) * inv;
    *(float4*)(O + i) = o;
}

// ---------------------------------------------------------------------------
// Fallback (round-1 kernel, known-good) if workspace is too small.
// ---------------------------------------------------------------------------
#define KP 72
#define FBR 64
__global__ __launch_bounds__(256, 2)
void fa_fallback(const float* __restrict__ Q, const float* __restrict__ K,
                 const float* __restrict__ V, const int* __restrict__ M,
                 float* __restrict__ O)
{
    __shared__ unsigned short KsF[BC][KP];
    __shared__ unsigned short VsF[DD][KP];
    __shared__ unsigned short PsF[4][16][KP];
    __shared__ float mb[BC];

    const int blk = blockIdx.x;
    const int qt = blk % (SS / FBR);
    const int bh = blk / (SS / FBR);
    const int b = bh / HH;
    const int h = bh % HH;
    const int tid = threadIdx.x;
    const int wave = tid >> 6;
    const int lane = tid & 63;
    const int lq = lane & 15;
    const int quad = lane >> 4;

    const int qrow = qt * FBR + wave * 16 + lq;
    const float* qp = Q + (((size_t)b * SS + qrow) * HH + h) * DD;
    short8 qf[2];
    #pragma unroll
    for (int c = 0; c < 2; ++c) {
        const float4 f0 = *(const float4*)(qp + c * 32 + quad * 8);
        const float4 f1 = *(const float4*)(qp + c * 32 + quad * 8 + 4);
        short8 t;
        t[0] = (short)f2bf(f0.x * 0.125f); t[1] = (short)f2bf(f0.y * 0.125f);
        t[2] = (short)f2bf(f0.z * 0.125f); t[3] = (short)f2bf(f0.w * 0.125f);
        t[4] = (short)f2bf(f1.x * 0.125f); t[5] = (short)f2bf(f1.y * 0.125f);
        t[6] = (short)f2bf(f1.z * 0.125f); t[7] = (short)f2bf(f1.w * 0.125f);
        qf[c] = t;
    }
    f32x4 acc[4];
    #pragma unroll
    for (int dt = 0; dt < 4; ++dt) acc[dt] = (f32x4){0.f, 0.f, 0.f, 0.f};
    float m_i[4] = {-1e30f, -1e30f, -1e30f, -1e30f};
    float l_i[4] = {0.f, 0.f, 0.f, 0.f};

    const int sr = tid >> 2;
    const int sc = tid & 3;
    const size_t rowstride = (size_t)HH * DD;
    const float* kbase = K + (((size_t)b * SS) * HH + h) * DD;
    const float* vbase = V + (((size_t)b * SS) * HH + h) * DD;

    for (int kt = 0; kt < NT; ++kt) {
        const int k0 = kt * BC;
        __syncthreads();
        {
            const float* kp = kbase + (size_t)(k0 + sr) * rowstride + sc * 16;
            #pragma unroll
            for (int i = 0; i < 4; ++i) {
                const float4 f = *(const float4*)(kp + i * 4);
                ushort4_t u;
                u[0] = f2bf(f.x); u[1] = f2bf(f.y); u[2] = f2bf(f.z); u[3] = f2bf(f.w);
                *(ushort4_t*)&KsF[sr][sc * 16 + i * 4] = u;
            }
            const float* vp = vbase + (size_t)(k0 + sr) * rowstride + sc * 16;
            #pragma unroll
            for (int i = 0; i < 4; ++i) {
                const float4 f = *(const float4*)(vp + i * 4);
                const int d = sc * 16 + i * 4;
                VsF[d + 0][sr] = f2bf(f.x); VsF[d + 1][sr] = f2bf(f.y);
                VsF[d + 2][sr] = f2bf(f.z); VsF[d + 3][sr] = f2bf(f.w);
            }
            if (tid < BC) mb[tid] = M[(size_t)b * SS + k0 + tid] ? -1e30f : 0.0f;
        }
        __syncthreads();
        f32x4 s[4];
        #pragma unroll
        for (int ct = 0; ct < 4; ++ct) {
            f32x4 z = (f32x4){0.f, 0.f, 0.f, 0.f};
            const unsigned short* kr = &KsF[ct * 16 + lq][quad * 8];
            const short8 kf0 = *(const short8*)kr;
            const short8 kf1 = *(const short8*)(kr + 32);
            z = __builtin_amdgcn_mfma_f32_16x16x32_bf16(qf[0], kf0, z, 0, 0, 0);
            z = __builtin_amdgcn_mfma_f32_16x16x32_bf16(qf[1], kf1, z, 0, 0, 0);
            s[ct] = z;
        }
        #pragma unroll
        for (int ct = 0; ct < 4; ++ct) {
            const float mbias = mb[ct * 16 + lq];
            s[ct][0] += mbias; s[ct][1] += mbias; s[ct][2] += mbias; s[ct][3] += mbias;
        }
        #pragma unroll
        for (int r = 0; r < 4; ++r) {
            float mx = fmaxf(fmaxf(s[0][r], s[1][r]), fmaxf(s[2][r], s[3][r]));
            mx = fmaxf(mx, __shfl_xor(mx, 1));
            mx = fmaxf(mx, __shfl_xor(mx, 2));
            mx = fmaxf(mx, __shfl_xor(mx, 4));
            mx = fmaxf(mx, __shfl_xor(mx, 8));
            const float m_new = fmaxf(m_i[r], mx);
            const float alpha = __expf(m_i[r] - m_new);
            m_i[r] = m_new;
            float rs = 0.f;
            #pragma unroll
            for (int ct = 0; ct < 4; ++ct) {
                const float p = __expf(s[ct][r] - m_new);
                rs += p;
                PsF[wave][quad * 4 + r][ct * 16 + lq] = f2bf(p);
            }
            rs += __shfl_xor(rs, 1); rs += __shfl_xor(rs, 2);
            rs += __shfl_xor(rs, 4); rs += __shfl_xor(rs, 8);
            l_i[r] = l_i[r] * alpha + rs;
            #pragma unroll
            for (int dt = 0; dt < 4; ++dt) acc[dt][r] *= alpha;
        }
        const unsigned short* pr = &PsF[wave][lq][quad * 8];
        const short8 pf0 = *(const short8*)pr;
        const short8 pf1 = *(const short8*)(pr + 32);
        #pragma unroll
        for (int dt = 0; dt < 4; ++dt) {
            const unsigned short* vr = &VsF[dt * 16 + lq][quad * 8];
            const short8 vf0 = *(const short8*)vr;
            const short8 vf1 = *(const short8*)(vr + 32);
            acc[dt] = __builtin_amdgcn_mfma_f32_16x16x32_bf16(pf0, vf0, acc[dt], 0, 0, 0);
            acc[dt] = __builtin_amdgcn_mfma_f32_16x16x32_bf16(pf1, vf1, acc[dt], 0, 0, 0);
        }
    }
    #pragma unroll
    for (int r = 0; r < 4; ++r) {
        const float inv = 1.0f / l_i[r];
        const int row = qt * FBR + wave * 16 + quad * 4 + r;
        float* op = O + (((size_t)b * SS + row) * HH + h) * DD;
        #pragma unroll
        for (int dt = 0; dt < 4; ++dt)
            op[dt * 16 + lq] = acc[dt][r] * inv;
    }
}

extern "C" void kernel_launch(void* const* d_in, const int* in_sizes, int n_in,
                              void* d_out, int out_size, void* d_ws, size_t ws_size,
                              hipStream_t stream) {
    const float* q = (const float*)d_in[0];
    const float* k = (const float*)d_in[1];
    const float* v = (const float*)d_in[2];
    const int*   m = (const int*)d_in[3];
    float* out = (float*)d_out;

    const int nprep = BB * HH * NT;                      // 1024
    const size_t kb_bytes = (size_t)nprep * TILE_E * 2;  // 8 MB
    const size_t ou_bytes = (size_t)2 * OSZ * 4;         // 32 MB
    const size_t lp_bytes = (size_t)2 * BB * HH * SS * 4;// 512 KB
    const size_t mc_bytes = (size_t)BB * NT * 4;         // 256 B

    const size_t need_split  = 2 * kb_bytes + ou_bytes + lp_bytes + mc_bytes;
    const size_t need_single = 2 * kb_bytes + mc_bytes;

    if (ws_size >= need_single) {
        unsigned short* Kb = (unsigned short*)d_ws;
        unsigned short* Vt = (unsigned short*)((char*)d_ws + kb_bytes);
        char* rest = (char*)d_ws + 2 * kb_bytes;
        if (ws_size >= need_split) {
            float* Ou = (float*)rest;
            float* Lp = (float*)(rest + ou_bytes);
            int* mcnt = (int*)(rest + ou_bytes + lp_bytes);
            prep_kernel<<<nprep, 256, 0, stream>>>(k, v, m, Kb, Vt, mcnt);
            fa3_kernel<true><<<2 * BB * HH * NQT, 256, 0, stream>>>(
                q, Kb, Vt, mcnt, Ou, Lp);
            combine_kernel<<<OSZ / 4 / 256, 256, 0, stream>>>(Ou, Lp, out);
        } else {
            int* mcnt = (int*)rest;
            prep_kernel<<<nprep, 256, 0, stream>>>(k, v, m, Kb, Vt, mcnt);
            fa3_kernel<false><<<BB * HH * NQT, 256, 0, stream>>>(
                q, Kb, Vt, mcnt, out, nullptr);
        }
    } else {
        fa_fallback<<<BB * HH * (SS / FBR), 256, 0, stream>>>(q, k, v, m, out);
    }
}

// Round 6
// 144.969 us; speedup vs baseline: 1.0607x; 1.0229x over previous
//
#include <hip/hip_runtime.h>
#include <hip/hip_bf16.h>

// (B,S,H,D) = (2,2048,16,64), fp32 in/out, int32 mask (True -> -inf).
#define BB 2
#define SS 2048
#define HH 16
#define DD 64
#define BR 128         // query rows per block (4 waves x 32)
#define BC 64          // keys per inner tile
#define NT (SS / BC)   // 32 key tiles
#define NQT (SS / BR)  // 16 query tiles
#define TILE_E (BC * DD)        // 4096 bf16 elems = 8 KB per tile
#define LOG2E 1.44269504f
#define LSTR 72        // prep LDS transpose row stride (ushort)
#define OSZ (BB * SS * HH * DD)   // 4M output elems

typedef __attribute__((ext_vector_type(8))) short short8;
typedef __attribute__((ext_vector_type(4))) float f32x4;
typedef __attribute__((ext_vector_type(16))) float f32x16;
typedef __attribute__((ext_vector_type(4))) unsigned int uint32x4;
typedef __attribute__((ext_vector_type(4))) unsigned short ushort4_t;

// fp32 -> bf16 RNE (scalar fallback / prep V path)
static __device__ __forceinline__ unsigned short f2bf(float f) {
    unsigned int u = __float_as_uint(f);
    unsigned int r = u + 0x7FFFu + ((u >> 16) & 1u);
    return (unsigned short)(r >> 16);
}
// fp32 pair -> packed bf16x2 via single v_cvt_pk_bf16_f32 (RNE, same bits as f2bf)
static __device__ __forceinline__ unsigned int cvtpk(float lo, float hi) {
    unsigned int r;
    asm("v_cvt_pk_bf16_f32 %0, %1, %2" : "=v"(r) : "v"(lo), "v"(hi));
    return r;
}
// swap upper 32 lanes of a with lower 32 lanes of b (one VALU op, no LDS pipe)
static __device__ __forceinline__ void pl32swap(unsigned int &a, unsigned int &b) {
#if __has_builtin(__builtin_amdgcn_permlane32_swap)
    const auto r = __builtin_amdgcn_permlane32_swap((int)a, (int)b, false, false);
    a = (unsigned int)r[0];
    b = (unsigned int)r[1];
#else
    asm("v_permlane32_swap_b32 %0, %1" : "+v"(a), "+v"(b));
#endif
}
static __device__ __forceinline__ float fexp2(float x) {
#if __has_builtin(__builtin_amdgcn_exp2f)
    return __builtin_amdgcn_exp2f(x);
#else
    return exp2f(x);
#endif
}
// async global->LDS, 16B per lane
static __device__ __forceinline__ void gl_lds16(const void* g, void* l) {
    __builtin_amdgcn_global_load_lds(
        (const __attribute__((address_space(1))) void*)g,
        (__attribute__((address_space(3))) void*)l, 16, 0, 0);
}

// ---------------------------------------------------------------------------
// Pre-pass: K -> bf16 swizzled tiles with MASKED ROWS ZEROED, V -> bf16
// transposed tiles with masked rows zeroed, per-tile masked-key counts.
// Masked key k: K row 0 -> s=0 -> p=exp2(0)=1; V row 0 -> PV contrib 0;
// l corrected by subtracting the (integer) masked count. Exact.
// Tile layout (LDS-linear 8KB): elem offset r*64 + ((c ^ (r&7))*8) + j.
// ---------------------------------------------------------------------------
__global__ __launch_bounds__(256, 2)
void prep_kernel(const float* __restrict__ K, const float* __restrict__ V,
                 const int* __restrict__ M,
                 unsigned short* __restrict__ Kb, unsigned short* __restrict__ Vt,
                 int* __restrict__ mcnt)
{
    __shared__ unsigned short Vl[DD * LSTR];

    const int t  = blockIdx.x & (NT - 1);
    const int b  = blockIdx.x >> 9;
    const int bh = blockIdx.x >> 5;
    const int tid = threadIdx.x;
    const size_t tile = (size_t)blockIdx.x * TILE_E;
    const size_t rs = (size_t)HH * DD;
    const float* kb0 = K + (((size_t)b * SS + t * BC) * HH + (bh & 15)) * DD;
    const float* vb0 = V + (((size_t)b * SS + t * BC) * HH + (bh & 15)) * DD;
    const int* mrow = M + (size_t)b * SS + t * BC;

    // ---- K: coalesced read, zero masked rows, swizzled coalesced write ----
    {
        const int p  = tid & 7;
        const int r0 = tid >> 3;
        #pragma unroll
        for (int half = 0; half < 2; ++half) {
            const int r = r0 + half * 32;
            const int c = p ^ (r & 7);
            const float sel = mrow[r] ? 0.0f : 1.0f;
            const float* ks = kb0 + (size_t)r * rs + c * 8;
            const float4 f0 = *(const float4*)ks;
            const float4 f1 = *(const float4*)(ks + 4);
            uint32x4 u;
            u[0] = cvtpk(f0.x * sel, f0.y * sel);
            u[1] = cvtpk(f0.z * sel, f0.w * sel);
            u[2] = cvtpk(f1.x * sel, f1.y * sel);
            u[3] = cvtpk(f1.z * sel, f1.w * sel);
            *(uint32x4*)(Kb + tile + r * 64 + p * 8) = u;
        }
    }
    // ---- V: coalesced read, zero masked rows, LDS transpose, write ----
    {
        const int vr = tid >> 2;
        const int vc = tid & 3;
        const float sel = mrow[vr] ? 0.0f : 1.0f;
        const float* vp = vb0 + (size_t)vr * rs + vc * 16;
        #pragma unroll
        for (int i = 0; i < 4; ++i) {
            const float4 f = *(const float4*)(vp + i * 4);
            const int d = vc * 16 + i * 4;
            Vl[(d + 0) * LSTR + vr] = f2bf(f.x * sel);
            Vl[(d + 1) * LSTR + vr] = f2bf(f.y * sel);
            Vl[(d + 2) * LSTR + vr] = f2bf(f.z * sel);
            Vl[(d + 3) * LSTR + vr] = f2bf(f.w * sel);
        }
    }
    __syncthreads();
    {
        const int p  = tid & 7;
        const int r0 = tid >> 3;
        #pragma unroll
        for (int half = 0; half < 2; ++half) {
            const int r = r0 + half * 32;
            const int c = p ^ (r & 7);
            const short8 o = *(const short8*)&Vl[r * LSTR + c * 8];
            *(short8*)(Vt + tile + r * 64 + p * 8) = o;
        }
    }
    // ---- masked-key count for this tile ----
    if ((bh & 15) == 0 && tid < 64) {
        const unsigned long long bal = __ballot(mrow[tid] != 0);
        if (tid == 0) mcnt[b * NT + t] = (int)__popcll(bal);
    }
}

// ---------------------------------------------------------------------------
// Flash kernel: 32x32x16 MFMA, S^T formulation, P redistribution via
// v_cvt_pk_bf16_f32 + v_permlane32_swap_b32 (T12), mask pre-baked into K/V,
// double-buffered staging. Bijective chunked XCD swizzle: each XCD gets a
// contiguous logical chunk (8 bh x 16 qt -> 2MB K/V set fits 4MB L2), so
// staging loads hit L2 and the per-iter vmcnt(0) drain shortens.
// NOTE: __launch_bounds__ min-waves MUST stay 2 — (256,3) and (256,4) both
// produce wrong results (R3/R4/R5 bisect); mechanism unidentified.
// SPLIT: 2-way key split with unnormalized partials + l sums to workspace.
// ---------------------------------------------------------------------------
template<bool SPLIT>
__global__ __launch_bounds__(256, 2)
void fa3_kernel(const float* __restrict__ Q,
                const unsigned short* __restrict__ Kb,
                const unsigned short* __restrict__ Vt,
                const int* __restrict__ mcnt,
                float* __restrict__ Op,      // SPLIT: partials; else final O
                float* __restrict__ Lp)      // SPLIT: l partials; else unused
{
    __shared__ __align__(16) unsigned short Ks[2][TILE_E];
    __shared__ __align__(16) unsigned short Vs[2][TILE_E];

    // bijective chunked XCD swizzle (grid 1024 or 512, both % 8 == 0):
    // hardware ids round-robin XCDs (id%8); XCD j thus executes logical
    // ids [j*cpx, (j+1)*cpx) — blocks sharing bh land on one XCD's L2.
    const int nwg  = (SPLIT ? 2 * BB * HH * NQT : BB * HH * NQT);
    const int cpx  = nwg >> 3;
    const int blk  = (blockIdx.x & 7) * cpx + (blockIdx.x >> 3);

    const int qt  = blk & (NQT - 1);
    const int bh  = (blk >> 4) & 31;
    const int spl = SPLIT ? (blk >> 9) : 0;
    const int b   = bh >> 4;
    const int h   = bh & 15;
    const int kt0 = SPLIT ? spl * (NT / 2) : 0;
    const int ktn = SPLIT ? (NT / 2) : NT;

    const int tid  = threadIdx.x;
    const int wave = tid >> 6;
    const int lane = tid & 63;
    const int ln   = lane & 31;
    const int l5   = lane >> 5;

    // ---- Q fragments: B-operand B[k=d][n=q], n=ln, k=l5*8+j per d-step ----
    const float qscale = 0.125f * LOG2E;
    const int qrow = qt * BR + wave * 32 + ln;
    const float* qp = Q + (((size_t)b * SS + qrow) * HH + h) * DD;
    short8 qf[4];
    #pragma unroll
    for (int t = 0; t < 4; ++t) {
        const int d0 = t * 16 + l5 * 8;
        const float4 f0 = *(const float4*)(qp + d0);
        const float4 f1 = *(const float4*)(qp + d0 + 4);
        uint32x4 u;
        u[0] = cvtpk(f0.x * qscale, f0.y * qscale);
        u[1] = cvtpk(f0.z * qscale, f0.w * qscale);
        u[2] = cvtpk(f1.x * qscale, f1.y * qscale);
        u[3] = cvtpk(f1.z * qscale, f1.w * qscale);
        qf[t] = __builtin_bit_cast(short8, u);
    }

    // masked-key correction for this block's key range (uniform scalar loads)
    int corr = 0;
    for (int i = 0; i < ktn; ++i) corr += mcnt[b * NT + kt0 + i];

    f32x16 acc0, acc1;
    #pragma unroll
    for (int i = 0; i < 16; ++i) { acc0[i] = 0.f; acc1[i] = 0.f; }
    f32x4 lsum4 = {0.f, 0.f, 0.f, 0.f};

    const unsigned short* kb_bh = Kb + (size_t)bh * NT * TILE_E;
    const unsigned short* vt_bh = Vt + (size_t)bh * NT * TILE_E;
    const int we = wave * 1024;
    const int wb = wave * 2048;

    // ---- prologue: stage first tile into buffer 0 ----
    {
        const unsigned short* kbt = kb_bh + (size_t)kt0 * TILE_E;
        const unsigned short* vtt = vt_bh + (size_t)kt0 * TILE_E;
        gl_lds16(kbt + we + lane * 8,       (char*)Ks[0] + wb);
        gl_lds16(kbt + we + 512 + lane * 8, (char*)Ks[0] + wb + 1024);
        gl_lds16(vtt + we + lane * 8,       (char*)Vs[0] + wb);
        gl_lds16(vtt + we + 512 + lane * 8, (char*)Vs[0] + wb + 1024);
    }
    __syncthreads();

    const int pswz = (ln & 7);

    for (int it = 0; it < ktn; ++it) {
        const int cur = it & 1;
        const int nxt = cur ^ 1;
        const int kn = kt0 + ((it + 1 < ktn) ? it + 1 : it);
        const unsigned short* kbt = kb_bh + (size_t)kn * TILE_E;
        const unsigned short* vtt = vt_bh + (size_t)kn * TILE_E;
        gl_lds16(kbt + we + lane * 8,       (char*)Ks[nxt] + wb);
        gl_lds16(kbt + we + 512 + lane * 8, (char*)Ks[nxt] + wb + 1024);
        gl_lds16(vtt + we + lane * 8,       (char*)Vs[nxt] + wb);
        gl_lds16(vtt + we + 512 + lane * 8, (char*)Vs[nxt] + wb + 1024);

        // ---- S^T = K Q^T ----
        f32x16 s0, s1;
        #pragma unroll
        for (int i = 0; i < 16; ++i) { s0[i] = 0.f; s1[i] = 0.f; }
        #pragma unroll
        for (int t = 0; t < 4; ++t) {
            const int p = (2 * t + l5) ^ pswz;
            const short8 kf0 = *(const short8*)(Ks[cur] + ln * 64 + p * 8);
            const short8 kf1 = *(const short8*)(Ks[cur] + (32 + ln) * 64 + p * 8);
            s0 = __builtin_amdgcn_mfma_f32_32x32x16_bf16(kf0, qf[t], s0, 0, 0, 0);
            s1 = __builtin_amdgcn_mfma_f32_32x32x16_bf16(kf1, qf[t], s1, 0, 0, 0);
        }

        // ---- exp2 + lsum (v_pk_add_f32) + pack (v_cvt_pk_bf16_f32) ----
        unsigned int pk[2][8];
        #pragma unroll
        for (int hh = 0; hh < 2; ++hh) {
            #pragma unroll
            for (int g = 0; g < 4; ++g) {
                const float p0 = fexp2(hh ? s1[g * 4 + 0] : s0[g * 4 + 0]);
                const float p1 = fexp2(hh ? s1[g * 4 + 1] : s0[g * 4 + 1]);
                const float p2 = fexp2(hh ? s1[g * 4 + 2] : s0[g * 4 + 2]);
                const float p3 = fexp2(hh ? s1[g * 4 + 3] : s0[g * 4 + 3]);
                lsum4 += (f32x4){p0, p1, p2, p3};
                pk[hh][g * 2 + 0] = cvtpk(p0, p1);
                pk[hh][g * 2 + 1] = cvtpk(p2, p3);
            }
        }
        // ---- cross-half redistribution: 8 permlane32_swap, no LDS pipe ----
        #pragma unroll
        for (int hh = 0; hh < 2; ++hh) {
            pl32swap(pk[hh][0], pk[hh][2]);
            pl32swap(pk[hh][1], pk[hh][3]);
            pl32swap(pk[hh][4], pk[hh][6]);
            pl32swap(pk[hh][5], pk[hh][7]);
        }
        short8 pf[4];
        #pragma unroll
        for (int t = 0; t < 4; ++t) {
            const int hh = t >> 1;
            const int s4 = (t & 1) * 4;
            uint32x4 u;
            u[0] = pk[hh][s4 + 0];
            u[1] = pk[hh][s4 + 1];
            u[2] = pk[hh][s4 + 2];
            u[3] = pk[hh][s4 + 3];
            pf[t] = __builtin_bit_cast(short8, u);
        }

        // ---- O^T += V^T P^T ----
        #pragma unroll
        for (int t = 0; t < 4; ++t) {
            const int p = (2 * t + l5) ^ pswz;
            const short8 vf0 = *(const short8*)(Vs[cur] + ln * 64 + p * 8);
            const short8 vf1 = *(const short8*)(Vs[cur] + (32 + ln) * 64 + p * 8);
            acc0 = __builtin_amdgcn_mfma_f32_32x32x16_bf16(vf0, pf[t], acc0, 0, 0, 0);
            acc1 = __builtin_amdgcn_mfma_f32_32x32x16_bf16(vf1, pf[t], acc1, 0, 0, 0);
        }

        __syncthreads();
    }

    // ---- epilogue ----
    const float lsum = (lsum4[0] + lsum4[1]) + (lsum4[2] + lsum4[3]);
    const float l = lsum + __shfl_xor(lsum, 32) - (float)corr;
    if (SPLIT) {
        float* op = Op + (size_t)spl * OSZ + (((size_t)b * SS + qrow) * HH + h) * DD;
        #pragma unroll
        for (int dh = 0; dh < 2; ++dh) {
            #pragma unroll
            for (int g = 0; g < 4; ++g) {
                const int d0 = dh * 32 + 8 * g + 4 * l5;
                float4 o;
                o.x = dh ? acc1[g * 4 + 0] : acc0[g * 4 + 0];
                o.y = dh ? acc1[g * 4 + 1] : acc0[g * 4 + 1];
                o.z = dh ? acc1[g * 4 + 2] : acc0[g * 4 + 2];
                o.w = dh ? acc1[g * 4 + 3] : acc0[g * 4 + 3];
                *(float4*)(op + d0) = o;
            }
        }
        if (l5 == 0)
            Lp[spl * (BB * HH * SS) + (b * HH + h) * SS + qrow] = l;
    } else {
        const float inv = 1.0f / l;
        float* op = Op + (((size_t)b * SS + qrow) * HH + h) * DD;
        #pragma unroll
        for (int dh = 0; dh < 2; ++dh) {
            #pragma unroll
            for (int g = 0; g < 4; ++g) {
                const int d0 = dh * 32 + 8 * g + 4 * l5;
                float4 o;
                o.x = (dh ? acc1[g * 4 + 0] : acc0[g * 4 + 0]) * inv;
                o.y = (dh ? acc1[g * 4 + 1] : acc0[g * 4 + 1]) * inv;
                o.z = (dh ? acc1[g * 4 + 2] : acc0[g * 4 + 2]) * inv;
                o.w = (dh ? acc1[g * 4 + 3] : acc0[g * 4 + 3]) * inv;
                *(float4*)(op + d0) = o;
            }
        }
    }
}

// ---------------------------------------------------------------------------
// Combine: O = (Ou0 + Ou1) / (l0 + l1), float4 per thread.
// ---------------------------------------------------------------------------
__global__ __launch_bounds__(256, 4)
void combine_kernel(const float* __restrict__ Ou, const float* __restrict__ Lp,
                    float* __restrict__ O)
{
    const int gid = blockIdx.x * 256 + threadIdx.x;
    const int i = gid * 4;
    const int b   = i >> 21;             // S*H*D = 2^21
    const int row = (i >> 10) & (SS - 1);
    const int h   = (i >> 6) & (HH - 1);
    const int li  = (b * HH + h) * SS + row;
    const float l = Lp[li] + Lp[BB * HH * SS + li];
    const float inv = 1.0f / l;
    const float4 a = *(const float4*)(Ou + i);
    const float4 c = *(const float4*)(Ou + OSZ + i);
    float4 o;
    o.x = (a.x + c.x) * inv;
    o.y = (a.y + c.y) * inv;
    o.z = (a.z + c.z) * inv;
    o.w = (a.w + c.w) * inv;
    *(float4*)(O + i) = o;
}

// ---------------------------------------------------------------------------
// Fallback (round-1 kernel, known-good) if workspace is too small.
// ---------------------------------------------------------------------------
#define KP 72
#define FBR 64
__global__ __launch_bounds__(256, 2)
void fa_fallback(const float* __restrict__ Q, const float* __restrict__ K,
                 const float* __restrict__ V, const int* __restrict__ M,
                 float* __restrict__ O)
{
    __shared__ unsigned short KsF[BC][KP];
    __shared__ unsigned short VsF[DD][KP];
    __shared__ unsigned short PsF[4][16][KP];
    __shared__ float mb[BC];

    const int blk = blockIdx.x;
    const int qt = blk % (SS / FBR);
    const int bh = blk / (SS / FBR);
    const int b = bh / HH;
    const int h = bh % HH;
    const int tid = threadIdx.x;
    const int wave = tid >> 6;
    const int lane = tid & 63;
    const int lq = lane & 15;
    const int quad = lane >> 4;

    const int qrow = qt * FBR + wave * 16 + lq;
    const float* qp = Q + (((size_t)b * SS + qrow) * HH + h) * DD;
    short8 qf[2];
    #pragma unroll
    for (int c = 0; c < 2; ++c) {
        const float4 f0 = *(const float4*)(qp + c * 32 + quad * 8);
        const float4 f1 = *(const float4*)(qp + c * 32 + quad * 8 + 4);
        short8 t;
        t[0] = (short)f2bf(f0.x * 0.125f); t[1] = (short)f2bf(f0.y * 0.125f);
        t[2] = (short)f2bf(f0.z * 0.125f); t[3] = (short)f2bf(f0.w * 0.125f);
        t[4] = (short)f2bf(f1.x * 0.125f); t[5] = (short)f2bf(f1.y * 0.125f);
        t[6] = (short)f2bf(f1.z * 0.125f); t[7] = (short)f2bf(f1.w * 0.125f);
        qf[c] = t;
    }
    f32x4 acc[4];
    #pragma unroll
    for (int dt = 0; dt < 4; ++dt) acc[dt] = (f32x4){0.f, 0.f, 0.f, 0.f};
    float m_i[4] = {-1e30f, -1e30f, -1e30f, -1e30f};
    float l_i[4] = {0.f, 0.f, 0.f, 0.f};

    const int sr = tid >> 2;
    const int sc = tid & 3;
    const size_t rowstride = (size_t)HH * DD;
    const float* kbase = K + (((size_t)b * SS) * HH + h) * DD;
    const float* vbase = V + (((size_t)b * SS) * HH + h) * DD;

    for (int kt = 0; kt < NT; ++kt) {
        const int k0 = kt * BC;
        __syncthreads();
        {
            const float* kp = kbase + (size_t)(k0 + sr) * rowstride + sc * 16;
            #pragma unroll
            for (int i = 0; i < 4; ++i) {
                const float4 f = *(const float4*)(kp + i * 4);
                ushort4_t u;
                u[0] = f2bf(f.x); u[1] = f2bf(f.y); u[2] = f2bf(f.z); u[3] = f2bf(f.w);
                *(ushort4_t*)&KsF[sr][sc * 16 + i * 4] = u;
            }
            const float* vp = vbase + (size_t)(k0 + sr) * rowstride + sc * 16;
            #pragma unroll
            for (int i = 0; i < 4; ++i) {
                const float4 f = *(const float4*)(vp + i * 4);
                const int d = sc * 16 + i * 4;
                VsF[d + 0][sr] = f2bf(f.x); VsF[d + 1][sr] = f2bf(f.y);
                VsF[d + 2][sr] = f2bf(f.z); VsF[d + 3][sr] = f2bf(f.w);
            }
            if (tid < BC) mb[tid] = M[(size_t)b * SS + k0 + tid] ? -1e30f : 0.0f;
        }
        __syncthreads();
        f32x4 s[4];
        #pragma unroll
        for (int ct = 0; ct < 4; ++ct) {
            f32x4 z = (f32x4){0.f, 0.f, 0.f, 0.f};
            const unsigned short* kr = &KsF[ct * 16 + lq][quad * 8];
            const short8 kf0 = *(const short8*)kr;
            const short8 kf1 = *(const short8*)(kr + 32);
            z = __builtin_amdgcn_mfma_f32_16x16x32_bf16(qf[0], kf0, z, 0, 0, 0);
            z = __builtin_amdgcn_mfma_f32_16x16x32_bf16(qf[1], kf1, z, 0, 0, 0);
            s[ct] = z;
        }
        #pragma unroll
        for (int ct = 0; ct < 4; ++ct) {
            const float mbias = mb[ct * 16 + lq];
            s[ct][0] += mbias; s[ct][1] += mbias; s[ct][2] += mbias; s[ct][3] += mbias;
        }
        #pragma unroll
        for (int r = 0; r < 4; ++r) {
            float mx = fmaxf(fmaxf(s[0][r], s[1][r]), fmaxf(s[2][r], s[3][r]));
            mx = fmaxf(mx, __shfl_xor(mx, 1));
            mx = fmaxf(mx, __shfl_xor(mx, 2));
            mx = fmaxf(mx, __shfl_xor(mx, 4));
            mx = fmaxf(mx, __shfl_xor(mx, 8));
            const float m_new = fmaxf(m_i[r], mx);
            const float alpha = __expf(m_i[r] - m_new);
            m_i[r] = m_new;
            float rs = 0.f;
            #pragma unroll
            for (int ct = 0; ct < 4; ++ct) {
                const float p = __expf(s[ct][r] - m_new);
                rs += p;
                PsF[wave][quad * 4 + r][ct * 16 + lq] = f2bf(p);
            }
            rs += __shfl_xor(rs, 1); rs += __shfl_xor(rs, 2);
            rs += __shfl_xor(rs, 4); rs += __shfl_xor(rs, 8);
            l_i[r] = l_i[r] * alpha + rs;
            #pragma unroll
            for (int dt = 0; dt < 4; ++dt) acc[dt][r] *= alpha;
        }
        const unsigned short* pr = &PsF[wave][lq][quad * 8];
        const short8 pf0 = *(const short8*)pr;
        const short8 pf1 = *(const short8*)(pr + 32);
        #pragma unroll
        for (int dt = 0; dt < 4; ++dt) {
            const unsigned short* vr = &VsF[dt * 16 + lq][quad * 8];
            const short8 vf0 = *(const short8*)vr;
            const short8 vf1 = *(const short8*)(vr + 32);
            acc[dt] = __builtin_amdgcn_mfma_f32_16x16x32_bf16(pf0, vf0, acc[dt], 0, 0, 0);
            acc[dt] = __builtin_amdgcn_mfma_f32_16x16x32_bf16(pf1, vf1, acc[dt], 0, 0, 0);
        }
    }
    #pragma unroll
    for (int r = 0; r < 4; ++r) {
        const float inv = 1.0f / l_i[r];
        const int row = qt * FBR + wave * 16 + quad * 4 + r;
        float* op = O + (((size_t)b * SS + row) * HH + h) * DD;
        #pragma unroll
        for (int dt = 0; dt < 4; ++dt)
            op[dt * 16 + lq] = acc[dt][r] * inv;
    }
}

extern "C" void kernel_launch(void* const* d_in, const int* in_sizes, int n_in,
                              void* d_out, int out_size, void* d_ws, size_t ws_size,
                              hipStream_t stream) {
    const float* q = (const float*)d_in[0];
    const float* k = (const float*)d_in[1];
    const float* v = (const float*)d_in[2];
    const int*   m = (const int*)d_in[3];
    float* out = (float*)d_out;

    const int nprep = BB * HH * NT;                      // 1024
    const size_t kb_bytes = (size_t)nprep * TILE_E * 2;  // 8 MB
    const size_t ou_bytes = (size_t)2 * OSZ * 4;         // 32 MB
    const size_t lp_bytes = (size_t)2 * BB * HH * SS * 4;// 512 KB
    const size_t mc_bytes = (size_t)BB * NT * 4;         // 256 B

    const size_t need_split  = 2 * kb_bytes + ou_bytes + lp_bytes + mc_bytes;
    const size_t need_single = 2 * kb_bytes + mc_bytes;

    if (ws_size >= need_single) {
        unsigned short* Kb = (unsigned short*)d_ws;
        unsigned short* Vt = (unsigned short*)((char*)d_ws + kb_bytes);
        char* rest = (char*)d_ws + 2 * kb_bytes;
        if (ws_size >= need_split) {
            float* Ou = (float*)rest;
            float* Lp = (float*)(rest + ou_bytes);
            int* mcnt = (int*)(rest + ou_bytes + lp_bytes);
            prep_kernel<<<nprep, 256, 0, stream>>>(k, v, m, Kb, Vt, mcnt);
            fa3_kernel<true><<<2 * BB * HH * NQT, 256, 0, stream>>>(
                q, Kb, Vt, mcnt, Ou, Lp);
            combine_kernel<<<OSZ / 4 / 256, 256, 0, stream>>>(Ou, Lp, out);
        } else {
            int* mcnt = (int*)rest;
            prep_kernel<<<nprep, 256, 0, stream>>>(k, v, m, Kb, Vt, mcnt);
            fa3_kernel<false><<<BB * HH * NQT, 256, 0, stream>>>(
                q, Kb, Vt, mcnt, out, nullptr);
        }
    } else {
        fa_fallback<<<BB * HH * (SS / FBR), 256, 0, stream>>>(q, k, v, m, out);
    }
}

// Round 7
// 136.481 us; speedup vs baseline: 1.1267x; 1.0622x over previous
//
#include <hip/hip_runtime.h>
#include <hip/hip_bf16.h>

// (B,S,H,D) = (2,2048,16,64), fp32 in/out, int32 mask (True -> -inf).
#define BB 2
#define SS 2048
#define HH 16
#define DD 64
#define BR 128         // query rows per block (4 waves x 32)
#define BC 64          // keys per inner tile
#define NT (SS / BC)   // 32 key tiles
#define NQT (SS / BR)  // 16 query tiles
#define TILE_E (BC * DD)        // 4096 bf16 elems = 8 KB per tile
#define LOG2E 1.44269504f
#define LSTR 72        // prep LDS transpose row stride (ushort)
#define OSZ (BB * SS * HH * DD)   // 4M output elems

typedef __attribute__((ext_vector_type(8))) short short8;
typedef __attribute__((ext_vector_type(4))) float f32x4;
typedef __attribute__((ext_vector_type(16))) float f32x16;
typedef __attribute__((ext_vector_type(4))) unsigned int uint32x4;
typedef __attribute__((ext_vector_type(4))) unsigned short ushort4_t;

// fp32 -> bf16 RNE (scalar fallback / prep V path)
static __device__ __forceinline__ unsigned short f2bf(float f) {
    unsigned int u = __float_as_uint(f);
    unsigned int r = u + 0x7FFFu + ((u >> 16) & 1u);
    return (unsigned short)(r >> 16);
}
// fp32 pair -> packed bf16x2 via single v_cvt_pk_bf16_f32 (RNE, same bits as f2bf)
static __device__ __forceinline__ unsigned int cvtpk(float lo, float hi) {
    unsigned int r;
    asm("v_cvt_pk_bf16_f32 %0, %1, %2" : "=v"(r) : "v"(lo), "v"(hi));
    return r;
}
// swap upper 32 lanes of a with lower 32 lanes of b (one VALU op, no LDS pipe)
static __device__ __forceinline__ void pl32swap(unsigned int &a, unsigned int &b) {
#if __has_builtin(__builtin_amdgcn_permlane32_swap)
    const auto r = __builtin_amdgcn_permlane32_swap((int)a, (int)b, false, false);
    a = (unsigned int)r[0];
    b = (unsigned int)r[1];
#else
    asm("v_permlane32_swap_b32 %0, %1" : "+v"(a), "+v"(b));
#endif
}
static __device__ __forceinline__ float fexp2(float x) {
#if __has_builtin(__builtin_amdgcn_exp2f)
    return __builtin_amdgcn_exp2f(x);
#else
    return exp2f(x);
#endif
}
// async global->LDS, 16B per lane
static __device__ __forceinline__ void gl_lds16(const void* g, void* l) {
    __builtin_amdgcn_global_load_lds(
        (const __attribute__((address_space(1))) void*)g,
        (__attribute__((address_space(3))) void*)l, 16, 0, 0);
}

// ---------------------------------------------------------------------------
// Pre-pass: K -> bf16 swizzled tiles with MASKED ROWS ZEROED, V -> bf16
// transposed tiles with masked rows zeroed, per-tile masked-key counts.
// Masked key k: K row 0 -> s=0 -> p=exp2(0)=1; V row 0 -> PV contrib 0;
// l corrected by subtracting the (integer) masked count. Exact.
// Tile layout (LDS-linear 8KB): elem offset r*64 + ((c ^ (r&7))*8) + j.
// ---------------------------------------------------------------------------
__global__ __launch_bounds__(256, 2)
void prep_kernel(const float* __restrict__ K, const float* __restrict__ V,
                 const int* __restrict__ M,
                 unsigned short* __restrict__ Kb, unsigned short* __restrict__ Vt,
                 int* __restrict__ mcnt)
{
    __shared__ unsigned short Vl[DD * LSTR];

    const int t  = blockIdx.x & (NT - 1);
    const int b  = blockIdx.x >> 9;
    const int bh = blockIdx.x >> 5;
    const int tid = threadIdx.x;
    const size_t tile = (size_t)blockIdx.x * TILE_E;
    const size_t rs = (size_t)HH * DD;
    const float* kb0 = K + (((size_t)b * SS + t * BC) * HH + (bh & 15)) * DD;
    const float* vb0 = V + (((size_t)b * SS + t * BC) * HH + (bh & 15)) * DD;
    const int* mrow = M + (size_t)b * SS + t * BC;

    // ---- K: coalesced read, zero masked rows, swizzled coalesced write ----
    {
        const int p  = tid & 7;
        const int r0 = tid >> 3;
        #pragma unroll
        for (int half = 0; half < 2; ++half) {
            const int r = r0 + half * 32;
            const int c = p ^ (r & 7);
            const float sel = mrow[r] ? 0.0f : 1.0f;
            const float* ks = kb0 + (size_t)r * rs + c * 8;
            const float4 f0 = *(const float4*)ks;
            const float4 f1 = *(const float4*)(ks + 4);
            uint32x4 u;
            u[0] = cvtpk(f0.x * sel, f0.y * sel);
            u[1] = cvtpk(f0.z * sel, f0.w * sel);
            u[2] = cvtpk(f1.x * sel, f1.y * sel);
            u[3] = cvtpk(f1.z * sel, f1.w * sel);
            *(uint32x4*)(Kb + tile + r * 64 + p * 8) = u;
        }
    }
    // ---- V: coalesced read, zero masked rows, LDS transpose, write ----
    {
        const int vr = tid >> 2;
        const int vc = tid & 3;
        const float sel = mrow[vr] ? 0.0f : 1.0f;
        const float* vp = vb0 + (size_t)vr * rs + vc * 16;
        #pragma unroll
        for (int i = 0; i < 4; ++i) {
            const float4 f = *(const float4*)(vp + i * 4);
            const int d = vc * 16 + i * 4;
            Vl[(d + 0) * LSTR + vr] = f2bf(f.x * sel);
            Vl[(d + 1) * LSTR + vr] = f2bf(f.y * sel);
            Vl[(d + 2) * LSTR + vr] = f2bf(f.z * sel);
            Vl[(d + 3) * LSTR + vr] = f2bf(f.w * sel);
        }
    }
    __syncthreads();
    {
        const int p  = tid & 7;
        const int r0 = tid >> 3;
        #pragma unroll
        for (int half = 0; half < 2; ++half) {
            const int r = r0 + half * 32;
            const int c = p ^ (r & 7);
            const short8 o = *(const short8*)&Vl[r * LSTR + c * 8];
            *(short8*)(Vt + tile + r * 64 + p * 8) = o;
        }
    }
    // ---- masked-key count for this tile ----
    if ((bh & 15) == 0 && tid < 64) {
        const unsigned long long bal = __ballot(mrow[tid] != 0);
        if (tid == 0) mcnt[b * NT + t] = (int)__popcll(bal);
    }
}

// ---------------------------------------------------------------------------
// Flash kernel: 32x32x16 MFMA, S^T formulation, P redistribution via
// v_cvt_pk_bf16_f32 + v_permlane32_swap_b32 (T12), mask pre-baked into K/V,
// double-buffered staging. Bijective chunked XCD swizzle: each XCD gets a
// contiguous logical chunk (contiguous bh -> 2MB K/V set fits 4MB L2), so
// staging loads hit L2 (FETCH 78->25MB measured R6).
// NOTE: __launch_bounds__ min-waves MUST stay 2 — (256,3) and (256,4) both
// produce wrong results (R3/R4/R5 bisect); mechanism unidentified.
// Non-split mode (SPLIT=false) is the production path: 512 blocks = exactly
// 2/CU x 256 CU, one residency round, no combine pass.
// ---------------------------------------------------------------------------
template<bool SPLIT>
__global__ __launch_bounds__(256, 2)
void fa3_kernel(const float* __restrict__ Q,
                const unsigned short* __restrict__ Kb,
                const unsigned short* __restrict__ Vt,
                const int* __restrict__ mcnt,
                float* __restrict__ Op,      // SPLIT: partials; else final O
                float* __restrict__ Lp)      // SPLIT: l partials; else unused
{
    __shared__ __align__(16) unsigned short Ks[2][TILE_E];
    __shared__ __align__(16) unsigned short Vs[2][TILE_E];

    // bijective chunked XCD swizzle (grid 1024 or 512, both % 8 == 0):
    // hardware ids round-robin XCDs (id%8); XCD j thus executes logical
    // ids [j*cpx, (j+1)*cpx) — blocks sharing bh land on one XCD's L2.
    const int nwg  = (SPLIT ? 2 * BB * HH * NQT : BB * HH * NQT);
    const int cpx  = nwg >> 3;
    const int blk  = (blockIdx.x & 7) * cpx + (blockIdx.x >> 3);

    const int qt  = blk & (NQT - 1);
    const int bh  = (blk >> 4) & 31;
    const int spl = SPLIT ? (blk >> 9) : 0;
    const int b   = bh >> 4;
    const int h   = bh & 15;
    const int kt0 = SPLIT ? spl * (NT / 2) : 0;
    const int ktn = SPLIT ? (NT / 2) : NT;

    const int tid  = threadIdx.x;
    const int wave = tid >> 6;
    const int lane = tid & 63;
    const int ln   = lane & 31;
    const int l5   = lane >> 5;

    // ---- Q fragments: B-operand B[k=d][n=q], n=ln, k=l5*8+j per d-step ----
    const float qscale = 0.125f * LOG2E;
    const int qrow = qt * BR + wave * 32 + ln;
    const float* qp = Q + (((size_t)b * SS + qrow) * HH + h) * DD;
    short8 qf[4];
    #pragma unroll
    for (int t = 0; t < 4; ++t) {
        const int d0 = t * 16 + l5 * 8;
        const float4 f0 = *(const float4*)(qp + d0);
        const float4 f1 = *(const float4*)(qp + d0 + 4);
        uint32x4 u;
        u[0] = cvtpk(f0.x * qscale, f0.y * qscale);
        u[1] = cvtpk(f0.z * qscale, f0.w * qscale);
        u[2] = cvtpk(f1.x * qscale, f1.y * qscale);
        u[3] = cvtpk(f1.z * qscale, f1.w * qscale);
        qf[t] = __builtin_bit_cast(short8, u);
    }

    // masked-key correction for this block's key range (uniform scalar loads)
    int corr = 0;
    for (int i = 0; i < ktn; ++i) corr += mcnt[b * NT + kt0 + i];

    f32x16 acc0, acc1;
    #pragma unroll
    for (int i = 0; i < 16; ++i) { acc0[i] = 0.f; acc1[i] = 0.f; }
    f32x4 lsum4 = {0.f, 0.f, 0.f, 0.f};

    const unsigned short* kb_bh = Kb + (size_t)bh * NT * TILE_E;
    const unsigned short* vt_bh = Vt + (size_t)bh * NT * TILE_E;
    const int we = wave * 1024;
    const int wb = wave * 2048;

    // ---- prologue: stage first tile into buffer 0 ----
    {
        const unsigned short* kbt = kb_bh + (size_t)kt0 * TILE_E;
        const unsigned short* vtt = vt_bh + (size_t)kt0 * TILE_E;
        gl_lds16(kbt + we + lane * 8,       (char*)Ks[0] + wb);
        gl_lds16(kbt + we + 512 + lane * 8, (char*)Ks[0] + wb + 1024);
        gl_lds16(vtt + we + lane * 8,       (char*)Vs[0] + wb);
        gl_lds16(vtt + we + 512 + lane * 8, (char*)Vs[0] + wb + 1024);
    }
    __syncthreads();

    const int pswz = (ln & 7);

    for (int it = 0; it < ktn; ++it) {
        const int cur = it & 1;
        const int nxt = cur ^ 1;
        const int kn = kt0 + ((it + 1 < ktn) ? it + 1 : it);
        const unsigned short* kbt = kb_bh + (size_t)kn * TILE_E;
        const unsigned short* vtt = vt_bh + (size_t)kn * TILE_E;
        gl_lds16(kbt + we + lane * 8,       (char*)Ks[nxt] + wb);
        gl_lds16(kbt + we + 512 + lane * 8, (char*)Ks[nxt] + wb + 1024);
        gl_lds16(vtt + we + lane * 8,       (char*)Vs[nxt] + wb);
        gl_lds16(vtt + we + 512 + lane * 8, (char*)Vs[nxt] + wb + 1024);

        // ---- S^T = K Q^T ----
        f32x16 s0, s1;
        #pragma unroll
        for (int i = 0; i < 16; ++i) { s0[i] = 0.f; s1[i] = 0.f; }
        #pragma unroll
        for (int t = 0; t < 4; ++t) {
            const int p = (2 * t + l5) ^ pswz;
            const short8 kf0 = *(const short8*)(Ks[cur] + ln * 64 + p * 8);
            const short8 kf1 = *(const short8*)(Ks[cur] + (32 + ln) * 64 + p * 8);
            s0 = __builtin_amdgcn_mfma_f32_32x32x16_bf16(kf0, qf[t], s0, 0, 0, 0);
            s1 = __builtin_amdgcn_mfma_f32_32x32x16_bf16(kf1, qf[t], s1, 0, 0, 0);
        }

        // ---- exp2 + lsum (v_pk_add_f32) + pack (v_cvt_pk_bf16_f32) ----
        unsigned int pk[2][8];
        #pragma unroll
        for (int hh = 0; hh < 2; ++hh) {
            #pragma unroll
            for (int g = 0; g < 4; ++g) {
                const float p0 = fexp2(hh ? s1[g * 4 + 0] : s0[g * 4 + 0]);
                const float p1 = fexp2(hh ? s1[g * 4 + 1] : s0[g * 4 + 1]);
                const float p2 = fexp2(hh ? s1[g * 4 + 2] : s0[g * 4 + 2]);
                const float p3 = fexp2(hh ? s1[g * 4 + 3] : s0[g * 4 + 3]);
                lsum4 += (f32x4){p0, p1, p2, p3};
                pk[hh][g * 2 + 0] = cvtpk(p0, p1);
                pk[hh][g * 2 + 1] = cvtpk(p2, p3);
            }
        }
        // ---- cross-half redistribution: 8 permlane32_swap, no LDS pipe ----
        #pragma unroll
        for (int hh = 0; hh < 2; ++hh) {
            pl32swap(pk[hh][0], pk[hh][2]);
            pl32swap(pk[hh][1], pk[hh][3]);
            pl32swap(pk[hh][4], pk[hh][6]);
            pl32swap(pk[hh][5], pk[hh][7]);
        }
        short8 pf[4];
        #pragma unroll
        for (int t = 0; t < 4; ++t) {
            const int hh = t >> 1;
            const int s4 = (t & 1) * 4;
            uint32x4 u;
            u[0] = pk[hh][s4 + 0];
            u[1] = pk[hh][s4 + 1];
            u[2] = pk[hh][s4 + 2];
            u[3] = pk[hh][s4 + 3];
            pf[t] = __builtin_bit_cast(short8, u);
        }

        // ---- O^T += V^T P^T ----
        #pragma unroll
        for (int t = 0; t < 4; ++t) {
            const int p = (2 * t + l5) ^ pswz;
            const short8 vf0 = *(const short8*)(Vs[cur] + ln * 64 + p * 8);
            const short8 vf1 = *(const short8*)(Vs[cur] + (32 + ln) * 64 + p * 8);
            acc0 = __builtin_amdgcn_mfma_f32_32x32x16_bf16(vf0, pf[t], acc0, 0, 0, 0);
            acc1 = __builtin_amdgcn_mfma_f32_32x32x16_bf16(vf1, pf[t], acc1, 0, 0, 0);
        }

        __syncthreads();
    }

    // ---- epilogue ----
    const float lsum = (lsum4[0] + lsum4[1]) + (lsum4[2] + lsum4[3]);
    const float l = lsum + __shfl_xor(lsum, 32) - (float)corr;
    if (SPLIT) {
        float* op = Op + (size_t)spl * OSZ + (((size_t)b * SS + qrow) * HH + h) * DD;
        #pragma unroll
        for (int dh = 0; dh < 2; ++dh) {
            #pragma unroll
            for (int g = 0; g < 4; ++g) {
                const int d0 = dh * 32 + 8 * g + 4 * l5;
                float4 o;
                o.x = dh ? acc1[g * 4 + 0] : acc0[g * 4 + 0];
                o.y = dh ? acc1[g * 4 + 1] : acc0[g * 4 + 1];
                o.z = dh ? acc1[g * 4 + 2] : acc0[g * 4 + 2];
                o.w = dh ? acc1[g * 4 + 3] : acc0[g * 4 + 3];
                *(float4*)(op + d0) = o;
            }
        }
        if (l5 == 0)
            Lp[spl * (BB * HH * SS) + (b * HH + h) * SS + qrow] = l;
    } else {
        const float inv = 1.0f / l;
        float* op = Op + (((size_t)b * SS + qrow) * HH + h) * DD;
        #pragma unroll
        for (int dh = 0; dh < 2; ++dh) {
            #pragma unroll
            for (int g = 0; g < 4; ++g) {
                const int d0 = dh * 32 + 8 * g + 4 * l5;
                float4 o;
                o.x = (dh ? acc1[g * 4 + 0] : acc0[g * 4 + 0]) * inv;
                o.y = (dh ? acc1[g * 4 + 1] : acc0[g * 4 + 1]) * inv;
                o.z = (dh ? acc1[g * 4 + 2] : acc0[g * 4 + 2]) * inv;
                o.w = (dh ? acc1[g * 4 + 3] : acc0[g * 4 + 3]) * inv;
                *(float4*)(op + d0) = o;
            }
        }
    }
}

// ---------------------------------------------------------------------------
// Combine: O = (Ou0 + Ou1) / (l0 + l1), float4 per thread. (Unused in the
// non-split production path; kept for the split fallback.)
// ---------------------------------------------------------------------------
__global__ __launch_bounds__(256, 4)
void combine_kernel(const float* __restrict__ Ou, const float* __restrict__ Lp,
                    float* __restrict__ O)
{
    const int gid = blockIdx.x * 256 + threadIdx.x;
    const int i = gid * 4;
    const int b   = i >> 21;             // S*H*D = 2^21
    const int row = (i >> 10) & (SS - 1);
    const int h   = (i >> 6) & (HH - 1);
    const int li  = (b * HH + h) * SS + row;
    const float l = Lp[li] + Lp[BB * HH * SS + li];
    const float inv = 1.0f / l;
    const float4 a = *(const float4*)(Ou + i);
    const float4 c = *(const float4*)(Ou + OSZ + i);
    float4 o;
    o.x = (a.x + c.x) * inv;
    o.y = (a.y + c.y) * inv;
    o.z = (a.z + c.z) * inv;
    o.w = (a.w + c.w) * inv;
    *(float4*)(O + i) = o;
}

// ---------------------------------------------------------------------------
// Fallback (round-1 kernel, known-good) if workspace is too small.
// ---------------------------------------------------------------------------
#define KP 72
#define FBR 64
__global__ __launch_bounds__(256, 2)
void fa_fallback(const float* __restrict__ Q, const float* __restrict__ K,
                 const float* __restrict__ V, const int* __restrict__ M,
                 float* __restrict__ O)
{
    __shared__ unsigned short KsF[BC][KP];
    __shared__ unsigned short VsF[DD][KP];
    __shared__ unsigned short PsF[4][16][KP];
    __shared__ float mb[BC];

    const int blk = blockIdx.x;
    const int qt = blk % (SS / FBR);
    const int bh = blk / (SS / FBR);
    const int b = bh / HH;
    const int h = bh % HH;
    const int tid = threadIdx.x;
    const int wave = tid >> 6;
    const int lane = tid & 63;
    const int lq = lane & 15;
    const int quad = lane >> 4;

    const int qrow = qt * FBR + wave * 16 + lq;
    const float* qp = Q + (((size_t)b * SS + qrow) * HH + h) * DD;
    short8 qf[2];
    #pragma unroll
    for (int c = 0; c < 2; ++c) {
        const float4 f0 = *(const float4*)(qp + c * 32 + quad * 8);
        const float4 f1 = *(const float4*)(qp + c * 32 + quad * 8 + 4);
        short8 t;
        t[0] = (short)f2bf(f0.x * 0.125f); t[1] = (short)f2bf(f0.y * 0.125f);
        t[2] = (short)f2bf(f0.z * 0.125f); t[3] = (short)f2bf(f0.w * 0.125f);
        t[4] = (short)f2bf(f1.x * 0.125f); t[5] = (short)f2bf(f1.y * 0.125f);
        t[6] = (short)f2bf(f1.z * 0.125f); t[7] = (short)f2bf(f1.w * 0.125f);
        qf[c] = t;
    }
    f32x4 acc[4];
    #pragma unroll
    for (int dt = 0; dt < 4; ++dt) acc[dt] = (f32x4){0.f, 0.f, 0.f, 0.f};
    float m_i[4] = {-1e30f, -1e30f, -1e30f, -1e30f};
    float l_i[4] = {0.f, 0.f, 0.f, 0.f};

    const int sr = tid >> 2;
    const int sc = tid & 3;
    const size_t rowstride = (size_t)HH * DD;
    const float* kbase = K + (((size_t)b * SS) * HH + h) * DD;
    const float* vbase = V + (((size_t)b * SS) * HH + h) * DD;

    for (int kt = 0; kt < NT; ++kt) {
        const int k0 = kt * BC;
        __syncthreads();
        {
            const float* kp = kbase + (size_t)(k0 + sr) * rowstride + sc * 16;
            #pragma unroll
            for (int i = 0; i < 4; ++i) {
                const float4 f = *(const float4*)(kp + i * 4);
                ushort4_t u;
                u[0] = f2bf(f.x); u[1] = f2bf(f.y); u[2] = f2bf(f.z); u[3] = f2bf(f.w);
                *(ushort4_t*)&KsF[sr][sc * 16 + i * 4] = u;
            }
            const float* vp = vbase + (size_t)(k0 + sr) * rowstride + sc * 16;
            #pragma unroll
            for (int i = 0; i < 4; ++i) {
                const float4 f = *(const float4*)(vp + i * 4);
                const int d = sc * 16 + i * 4;
                VsF[d + 0][sr] = f2bf(f.x); VsF[d + 1][sr] = f2bf(f.y);
                VsF[d + 2][sr] = f2bf(f.z); VsF[d + 3][sr] = f2bf(f.w);
            }
            if (tid < BC) mb[tid] = M[(size_t)b * SS + k0 + tid] ? -1e30f : 0.0f;
        }
        __syncthreads();
        f32x4 s[4];
        #pragma unroll
        for (int ct = 0; ct < 4; ++ct) {
            f32x4 z = (f32x4){0.f, 0.f, 0.f, 0.f};
            const unsigned short* kr = &KsF[ct * 16 + lq][quad * 8];
            const short8 kf0 = *(const short8*)kr;
            const short8 kf1 = *(const short8*)(kr + 32);
            z = __builtin_amdgcn_mfma_f32_16x16x32_bf16(qf[0], kf0, z, 0, 0, 0);
            z = __builtin_amdgcn_mfma_f32_16x16x32_bf16(qf[1], kf1, z, 0, 0, 0);
            s[ct] = z;
        }
        #pragma unroll
        for (int ct = 0; ct < 4; ++ct) {
            const float mbias = mb[ct * 16 + lq];
            s[ct][0] += mbias; s[ct][1] += mbias; s[ct][2] += mbias; s[ct][3] += mbias;
        }
        #pragma unroll
        for (int r = 0; r < 4; ++r) {
            float mx = fmaxf(fmaxf(s[0][r], s[1][r]), fmaxf(s[2][r], s[3][r]));
            mx = fmaxf(mx, __shfl_xor(mx, 1));
            mx = fmaxf(mx, __shfl_xor(mx, 2));
            mx = fmaxf(mx, __shfl_xor(mx, 4));
            mx = fmaxf(mx, __shfl_xor(mx, 8));
            const float m_new = fmaxf(m_i[r], mx);
            const float alpha = __expf(m_i[r] - m_new);
            m_i[r] = m_new;
            float rs = 0.f;
            #pragma unroll
            for (int ct = 0; ct < 4; ++ct) {
                const float p = __expf(s[ct][r] - m_new);
                rs += p;
                PsF[wave][quad * 4 + r][ct * 16 + lq] = f2bf(p);
            }
            rs += __shfl_xor(rs, 1); rs += __shfl_xor(rs, 2);
            rs += __shfl_xor(rs, 4); rs += __shfl_xor(rs, 8);
            l_i[r] = l_i[r] * alpha + rs;
            #pragma unroll
            for (int dt = 0; dt < 4; ++dt) acc[dt][r] *= alpha;
        }
        const unsigned short* pr = &PsF[wave][lq][quad * 8];
        const short8 pf0 = *(const short8*)pr;
        const short8 pf1 = *(const short8*)(pr + 32);
        #pragma unroll
        for (int dt = 0; dt < 4; ++dt) {
            const unsigned short* vr = &VsF[dt * 16 + lq][quad * 8];
            const short8 vf0 = *(const short8*)vr;
            const short8 vf1 = *(const short8*)(vr + 32);
            acc[dt] = __builtin_amdgcn_mfma_f32_16x16x32_bf16(pf0, vf0, acc[dt], 0, 0, 0);
            acc[dt] = __builtin_amdgcn_mfma_f32_16x16x32_bf16(pf1, vf1, acc[dt], 0, 0, 0);
        }
    }
    #pragma unroll
    for (int r = 0; r < 4; ++r) {
        const float inv = 1.0f / l_i[r];
        const int row = qt * FBR + wave * 16 + quad * 4 + r;
        float* op = O + (((size_t)b * SS + row) * HH + h) * DD;
        #pragma unroll
        for (int dt = 0; dt < 4; ++dt)
            op[dt * 16 + lq] = acc[dt][r] * inv;
    }
}

extern "C" void kernel_launch(void* const* d_in, const int* in_sizes, int n_in,
                              void* d_out, int out_size, void* d_ws, size_t ws_size,
                              hipStream_t stream) {
    const float* q = (const float*)d_in[0];
    const float* k = (const float*)d_in[1];
    const float* v = (const float*)d_in[2];
    const int*   m = (const int*)d_in[3];
    float* out = (float*)d_out;

    const int nprep = BB * HH * NT;                      // 1024
    const size_t kb_bytes = (size_t)nprep * TILE_E * 2;  // 8 MB
    const size_t mc_bytes = (size_t)BB * NT * 4;         // 256 B
    const size_t need_single = 2 * kb_bytes + mc_bytes;  // 16 MB + 256 B

    if (ws_size >= need_single) {
        // Non-split path: 512 blocks = exactly 2/CU x 256 CU, one residency
        // round, no partials round-trip, no combine kernel. (Split path was
        // two rounds of 512 + a 48MB-traffic combine — strictly worse at
        // 2 blocks/CU capacity.)
        unsigned short* Kb = (unsigned short*)d_ws;
        unsigned short* Vt = (unsigned short*)((char*)d_ws + kb_bytes);
        int* mcnt = (int*)((char*)d_ws + 2 * kb_bytes);
        prep_kernel<<<nprep, 256, 0, stream>>>(k, v, m, Kb, Vt, mcnt);
        fa3_kernel<false><<<BB * HH * NQT, 256, 0, stream>>>(
            q, Kb, Vt, mcnt, out, nullptr);
    } else {
        fa_fallback<<<BB * HH * (SS / FBR), 256, 0, stream>>>(q, k, v, m, out);
    }
}

// Round 8
// 134.229 us; speedup vs baseline: 1.1456x; 1.0168x over previous
//
#include <hip/hip_runtime.h>
#include <hip/hip_bf16.h>

// (B,S,H,D) = (2,2048,16,64), fp32 in/out, int32 mask (True -> -inf).
#define BB 2
#define SS 2048
#define HH 16
#define DD 64
#define BR 128         // query rows per block (4 waves x 32)
#define BC 64          // keys per inner tile
#define NT (SS / BC)   // 32 key tiles
#define NQT (SS / BR)  // 16 query tiles
#define TILE_E (BC * DD)        // 4096 bf16 elems = 8 KB per tile
#define TILE_B (TILE_E * 2)     // 8192 bytes per tile
#define LOG2E 1.44269504f
#define LSTR 72        // prep LDS transpose row stride (ushort)
#define OSZ (BB * SS * HH * DD)   // 4M output elems

typedef __attribute__((ext_vector_type(8))) short short8;
typedef __attribute__((ext_vector_type(4))) float f32x4;
typedef __attribute__((ext_vector_type(16))) float f32x16;
typedef __attribute__((ext_vector_type(4))) unsigned int uint32x4;
typedef __attribute__((ext_vector_type(4))) unsigned short ushort4_t;

// fp32 -> bf16 RNE (scalar fallback / prep V path)
static __device__ __forceinline__ unsigned short f2bf(float f) {
    unsigned int u = __float_as_uint(f);
    unsigned int r = u + 0x7FFFu + ((u >> 16) & 1u);
    return (unsigned short)(r >> 16);
}
// fp32 pair -> packed bf16x2 via single v_cvt_pk_bf16_f32 (RNE, same bits as f2bf)
static __device__ __forceinline__ unsigned int cvtpk(float lo, float hi) {
    unsigned int r;
    asm("v_cvt_pk_bf16_f32 %0, %1, %2" : "=v"(r) : "v"(lo), "v"(hi));
    return r;
}
// swap upper 32 lanes of a with lower 32 lanes of b (one VALU op, no LDS pipe)
static __device__ __forceinline__ void pl32swap(unsigned int &a, unsigned int &b) {
#if __has_builtin(__builtin_amdgcn_permlane32_swap)
    const auto r = __builtin_amdgcn_permlane32_swap((int)a, (int)b, false, false);
    a = (unsigned int)r[0];
    b = (unsigned int)r[1];
#else
    asm("v_permlane32_swap_b32 %0, %1" : "+v"(a), "+v"(b));
#endif
}
static __device__ __forceinline__ float fexp2(float x) {
#if __has_builtin(__builtin_amdgcn_exp2f)
    return __builtin_amdgcn_exp2f(x);
#else
    return exp2f(x);
#endif
}
// async global->LDS, 16B per lane
static __device__ __forceinline__ void gl_lds16(const void* g, void* l) {
    __builtin_amdgcn_global_load_lds(
        (const __attribute__((address_space(1))) void*)g,
        (__attribute__((address_space(3))) void*)l, 16, 0, 0);
}

// ---------------------------------------------------------------------------
// Pre-pass: K -> bf16 swizzled tiles with MASKED ROWS ZEROED, V -> bf16
// transposed tiles with masked rows zeroed, per-tile masked-key counts.
// Masked key k: K row 0 -> s=0 -> p=exp2(0)=1; V row 0 -> PV contrib 0;
// l corrected by subtracting the (integer) masked count. Exact.
// Tile layout (LDS-linear 8KB): elem offset r*64 + ((c ^ (r&7))*8) + j.
// ---------------------------------------------------------------------------
__global__ __launch_bounds__(256, 2)
void prep_kernel(const float* __restrict__ K, const float* __restrict__ V,
                 const int* __restrict__ M,
                 unsigned short* __restrict__ Kb, unsigned short* __restrict__ Vt,
                 int* __restrict__ mcnt)
{
    __shared__ unsigned short Vl[DD * LSTR];

    const int t  = blockIdx.x & (NT - 1);
    const int b  = blockIdx.x >> 9;
    const int bh = blockIdx.x >> 5;
    const int tid = threadIdx.x;
    const size_t tile = (size_t)blockIdx.x * TILE_E;
    const size_t rs = (size_t)HH * DD;
    const float* kb0 = K + (((size_t)b * SS + t * BC) * HH + (bh & 15)) * DD;
    const float* vb0 = V + (((size_t)b * SS + t * BC) * HH + (bh & 15)) * DD;
    const int* mrow = M + (size_t)b * SS + t * BC;

    // ---- K: coalesced read, zero masked rows, swizzled coalesced write ----
    {
        const int p  = tid & 7;
        const int r0 = tid >> 3;
        #pragma unroll
        for (int half = 0; half < 2; ++half) {
            const int r = r0 + half * 32;
            const int c = p ^ (r & 7);
            const float sel = mrow[r] ? 0.0f : 1.0f;
            const float* ks = kb0 + (size_t)r * rs + c * 8;
            const float4 f0 = *(const float4*)ks;
            const float4 f1 = *(const float4*)(ks + 4);
            uint32x4 u;
            u[0] = cvtpk(f0.x * sel, f0.y * sel);
            u[1] = cvtpk(f0.z * sel, f0.w * sel);
            u[2] = cvtpk(f1.x * sel, f1.y * sel);
            u[3] = cvtpk(f1.z * sel, f1.w * sel);
            *(uint32x4*)(Kb + tile + r * 64 + p * 8) = u;
        }
    }
    // ---- V: coalesced read, zero masked rows, LDS transpose, write ----
    {
        const int vr = tid >> 2;
        const int vc = tid & 3;
        const float sel = mrow[vr] ? 0.0f : 1.0f;
        const float* vp = vb0 + (size_t)vr * rs + vc * 16;
        #pragma unroll
        for (int i = 0; i < 4; ++i) {
            const float4 f = *(const float4*)(vp + i * 4);
            const int d = vc * 16 + i * 4;
            Vl[(d + 0) * LSTR + vr] = f2bf(f.x * sel);
            Vl[(d + 1) * LSTR + vr] = f2bf(f.y * sel);
            Vl[(d + 2) * LSTR + vr] = f2bf(f.z * sel);
            Vl[(d + 3) * LSTR + vr] = f2bf(f.w * sel);
        }
    }
    __syncthreads();
    {
        const int p  = tid & 7;
        const int r0 = tid >> 3;
        #pragma unroll
        for (int half = 0; half < 2; ++half) {
            const int r = r0 + half * 32;
            const int c = p ^ (r & 7);
            const short8 o = *(const short8*)&Vl[r * LSTR + c * 8];
            *(short8*)(Vt + tile + r * 64 + p * 8) = o;
        }
    }
    // ---- masked-key count for this tile ----
    if ((bh & 15) == 0 && tid < 64) {
        const unsigned long long bal = __ballot(mrow[tid] != 0);
        if (tid == 0) mcnt[b * NT + t] = (int)__popcll(bal);
    }
}

// ---------------------------------------------------------------------------
// Flash kernel: 32x32x16 MFMA, S^T formulation, P redistribution via
// v_cvt_pk_bf16_f32 + v_permlane32_swap_b32 (T12), mask pre-baked into K/V,
// double-buffered staging with TWO K-tiles per barrier (halves the per-iter
// vmcnt(0)+lgkmcnt(0) barrier-drain stall, which dominates: 45% no-issue at
// R7). LDS 64KB/block, 2 blocks/CU. Bijective chunked XCD swizzle keeps each
// XCD's K/V slice L2-resident (FETCH 78->16MB measured R6/R7).
// NOTE: __launch_bounds__ min-waves MUST stay 2 — (256,3) and (256,4) both
// produce wrong results (R3/R4/R5 bisect); mechanism unidentified.
// ---------------------------------------------------------------------------
template<bool SPLIT>
__global__ __launch_bounds__(256, 2)
void fa3_kernel(const float* __restrict__ Q,
                const unsigned short* __restrict__ Kb,
                const unsigned short* __restrict__ Vt,
                const int* __restrict__ mcnt,
                float* __restrict__ Op,      // SPLIT: partials; else final O
                float* __restrict__ Lp)      // SPLIT: l partials; else unused
{
    __shared__ __align__(16) unsigned short Ks[2][2 * TILE_E];
    __shared__ __align__(16) unsigned short Vs[2][2 * TILE_E];

    // bijective chunked XCD swizzle (grid 512, % 8 == 0): hardware ids
    // round-robin XCDs (id%8); XCD j executes logical ids [j*cpx,(j+1)*cpx)
    // -> blocks sharing bh land on one XCD's L2.
    const int nwg  = (SPLIT ? 2 * BB * HH * NQT : BB * HH * NQT);
    const int cpx  = nwg >> 3;
    const int blk  = (blockIdx.x & 7) * cpx + (blockIdx.x >> 3);

    const int qt  = blk & (NQT - 1);
    const int bh  = (blk >> 4) & 31;
    const int spl = SPLIT ? (blk >> 9) : 0;
    const int b   = bh >> 4;
    const int h   = bh & 15;
    const int kt0 = SPLIT ? spl * (NT / 2) : 0;
    const int ktn = SPLIT ? (NT / 2) : NT;   // even in both modes

    const int tid  = threadIdx.x;
    const int wave = tid >> 6;
    const int lane = tid & 63;
    const int ln   = lane & 31;
    const int l5   = lane >> 5;

    // ---- Q fragments: B-operand B[k=d][n=q], n=ln, k=l5*8+j per d-step ----
    const float qscale = 0.125f * LOG2E;
    const int qrow = qt * BR + wave * 32 + ln;
    const float* qp = Q + (((size_t)b * SS + qrow) * HH + h) * DD;
    short8 qf[4];
    #pragma unroll
    for (int t = 0; t < 4; ++t) {
        const int d0 = t * 16 + l5 * 8;
        const float4 f0 = *(const float4*)(qp + d0);
        const float4 f1 = *(const float4*)(qp + d0 + 4);
        uint32x4 u;
        u[0] = cvtpk(f0.x * qscale, f0.y * qscale);
        u[1] = cvtpk(f0.z * qscale, f0.w * qscale);
        u[2] = cvtpk(f1.x * qscale, f1.y * qscale);
        u[3] = cvtpk(f1.z * qscale, f1.w * qscale);
        qf[t] = __builtin_bit_cast(short8, u);
    }

    // masked-key correction for this block's key range (uniform scalar loads)
    int corr = 0;
    for (int i = 0; i < ktn; ++i) corr += mcnt[b * NT + kt0 + i];

    f32x16 acc0, acc1;
    #pragma unroll
    for (int i = 0; i < 16; ++i) { acc0[i] = 0.f; acc1[i] = 0.f; }
    f32x4 lsum4 = {0.f, 0.f, 0.f, 0.f};

    const unsigned short* kb_bh = Kb + (size_t)bh * NT * TILE_E;
    const unsigned short* vt_bh = Vt + (size_t)bh * NT * TILE_E;
    const int we = wave * 1024;   // elems: wave's quarter of one tile
    const int wb = wave * 2048;   // bytes

    // ---- prologue: stage first tile PAIR into buffer 0 ----
    {
        const unsigned short* kbt = kb_bh + (size_t)kt0 * TILE_E;
        const unsigned short* vtt = vt_bh + (size_t)kt0 * TILE_E;
        #pragma unroll
        for (int s = 0; s < 2; ++s) {
            gl_lds16(kbt + s * TILE_E + we + lane * 8,       (char*)Ks[0] + s * TILE_B + wb);
            gl_lds16(kbt + s * TILE_E + we + 512 + lane * 8, (char*)Ks[0] + s * TILE_B + wb + 1024);
            gl_lds16(vtt + s * TILE_E + we + lane * 8,       (char*)Vs[0] + s * TILE_B + wb);
            gl_lds16(vtt + s * TILE_E + we + 512 + lane * 8, (char*)Vs[0] + s * TILE_B + wb + 1024);
        }
    }
    __syncthreads();

    const int pswz = (ln & 7);
    const int npair = ktn >> 1;

    for (int ii = 0; ii < npair; ++ii) {
        const int cur = ii & 1;
        const int nxt = cur ^ 1;
        const int kn = kt0 + 2 * ((ii + 1 < npair) ? ii + 1 : ii);
        const unsigned short* kbt = kb_bh + (size_t)kn * TILE_E;
        const unsigned short* vtt = vt_bh + (size_t)kn * TILE_E;
        #pragma unroll
        for (int s = 0; s < 2; ++s) {
            gl_lds16(kbt + s * TILE_E + we + lane * 8,       (char*)Ks[nxt] + s * TILE_B + wb);
            gl_lds16(kbt + s * TILE_E + we + 512 + lane * 8, (char*)Ks[nxt] + s * TILE_B + wb + 1024);
            gl_lds16(vtt + s * TILE_E + we + lane * 8,       (char*)Vs[nxt] + s * TILE_B + wb);
            gl_lds16(vtt + s * TILE_E + we + 512 + lane * 8, (char*)Vs[nxt] + s * TILE_B + wb + 1024);
        }

        #pragma unroll
        for (int sub = 0; sub < 2; ++sub) {
            const unsigned short* Kt = Ks[cur] + sub * TILE_E;
            const unsigned short* Vtl = Vs[cur] + sub * TILE_E;

            // ---- S^T = K Q^T ----
            f32x16 s0, s1;
            #pragma unroll
            for (int i = 0; i < 16; ++i) { s0[i] = 0.f; s1[i] = 0.f; }
            #pragma unroll
            for (int t = 0; t < 4; ++t) {
                const int p = (2 * t + l5) ^ pswz;
                const short8 kf0 = *(const short8*)(Kt + ln * 64 + p * 8);
                const short8 kf1 = *(const short8*)(Kt + (32 + ln) * 64 + p * 8);
                s0 = __builtin_amdgcn_mfma_f32_32x32x16_bf16(kf0, qf[t], s0, 0, 0, 0);
                s1 = __builtin_amdgcn_mfma_f32_32x32x16_bf16(kf1, qf[t], s1, 0, 0, 0);
            }

            // ---- exp2 + lsum (v_pk_add_f32) + pack (v_cvt_pk_bf16_f32) ----
            unsigned int pk[2][8];
            #pragma unroll
            for (int hh = 0; hh < 2; ++hh) {
                #pragma unroll
                for (int g = 0; g < 4; ++g) {
                    const float p0 = fexp2(hh ? s1[g * 4 + 0] : s0[g * 4 + 0]);
                    const float p1 = fexp2(hh ? s1[g * 4 + 1] : s0[g * 4 + 1]);
                    const float p2 = fexp2(hh ? s1[g * 4 + 2] : s0[g * 4 + 2]);
                    const float p3 = fexp2(hh ? s1[g * 4 + 3] : s0[g * 4 + 3]);
                    lsum4 += (f32x4){p0, p1, p2, p3};
                    pk[hh][g * 2 + 0] = cvtpk(p0, p1);
                    pk[hh][g * 2 + 1] = cvtpk(p2, p3);
                }
            }
            // ---- cross-half redistribution: 8 permlane32_swap ----
            #pragma unroll
            for (int hh = 0; hh < 2; ++hh) {
                pl32swap(pk[hh][0], pk[hh][2]);
                pl32swap(pk[hh][1], pk[hh][3]);
                pl32swap(pk[hh][4], pk[hh][6]);
                pl32swap(pk[hh][5], pk[hh][7]);
            }
            short8 pf[4];
            #pragma unroll
            for (int t = 0; t < 4; ++t) {
                const int hh = t >> 1;
                const int s4 = (t & 1) * 4;
                uint32x4 u;
                u[0] = pk[hh][s4 + 0];
                u[1] = pk[hh][s4 + 1];
                u[2] = pk[hh][s4 + 2];
                u[3] = pk[hh][s4 + 3];
                pf[t] = __builtin_bit_cast(short8, u);
            }

            // ---- O^T += V^T P^T ----
            #pragma unroll
            for (int t = 0; t < 4; ++t) {
                const int p = (2 * t + l5) ^ pswz;
                const short8 vf0 = *(const short8*)(Vtl + ln * 64 + p * 8);
                const short8 vf1 = *(const short8*)(Vtl + (32 + ln) * 64 + p * 8);
                acc0 = __builtin_amdgcn_mfma_f32_32x32x16_bf16(vf0, pf[t], acc0, 0, 0, 0);
                acc1 = __builtin_amdgcn_mfma_f32_32x32x16_bf16(vf1, pf[t], acc1, 0, 0, 0);
            }
        }

        __syncthreads();
    }

    // ---- epilogue ----
    const float lsum = (lsum4[0] + lsum4[1]) + (lsum4[2] + lsum4[3]);
    const float l = lsum + __shfl_xor(lsum, 32) - (float)corr;
    if (SPLIT) {
        float* op = Op + (size_t)spl * OSZ + (((size_t)b * SS + qrow) * HH + h) * DD;
        #pragma unroll
        for (int dh = 0; dh < 2; ++dh) {
            #pragma unroll
            for (int g = 0; g < 4; ++g) {
                const int d0 = dh * 32 + 8 * g + 4 * l5;
                float4 o;
                o.x = dh ? acc1[g * 4 + 0] : acc0[g * 4 + 0];
                o.y = dh ? acc1[g * 4 + 1] : acc0[g * 4 + 1];
                o.z = dh ? acc1[g * 4 + 2] : acc0[g * 4 + 2];
                o.w = dh ? acc1[g * 4 + 3] : acc0[g * 4 + 3];
                *(float4*)(op + d0) = o;
            }
        }
        if (l5 == 0)
            Lp[spl * (BB * HH * SS) + (b * HH + h) * SS + qrow] = l;
    } else {
        const float inv = 1.0f / l;
        float* op = Op + (((size_t)b * SS + qrow) * HH + h) * DD;
        #pragma unroll
        for (int dh = 0; dh < 2; ++dh) {
            #pragma unroll
            for (int g = 0; g < 4; ++g) {
                const int d0 = dh * 32 + 8 * g + 4 * l5;
                float4 o;
                o.x = (dh ? acc1[g * 4 + 0] : acc0[g * 4 + 0]) * inv;
                o.y = (dh ? acc1[g * 4 + 1] : acc0[g * 4 + 1]) * inv;
                o.z = (dh ? acc1[g * 4 + 2] : acc0[g * 4 + 2]) * inv;
                o.w = (dh ? acc1[g * 4 + 3] : acc0[g * 4 + 3]) * inv;
                *(float4*)(op + d0) = o;
            }
        }
    }
}

// ---------------------------------------------------------------------------
// Fallback (round-1 kernel, known-good) if workspace is too small.
// ---------------------------------------------------------------------------
#define KP 72
#define FBR 64
__global__ __launch_bounds__(256, 2)
void fa_fallback(const float* __restrict__ Q, const float* __restrict__ K,
                 const float* __restrict__ V, const int* __restrict__ M,
                 float* __restrict__ O)
{
    __shared__ unsigned short KsF[BC][KP];
    __shared__ unsigned short VsF[DD][KP];
    __shared__ unsigned short PsF[4][16][KP];
    __shared__ float mb[BC];

    const int blk = blockIdx.x;
    const int qt = blk % (SS / FBR);
    const int bh = blk / (SS / FBR);
    const int b = bh / HH;
    const int h = bh % HH;
    const int tid = threadIdx.x;
    const int wave = tid >> 6;
    const int lane = tid & 63;
    const int lq = lane & 15;
    const int quad = lane >> 4;

    const int qrow = qt * FBR + wave * 16 + lq;
    const float* qp = Q + (((size_t)b * SS + qrow) * HH + h) * DD;
    short8 qf[2];
    #pragma unroll
    for (int c = 0; c < 2; ++c) {
        const float4 f0 = *(const float4*)(qp + c * 32 + quad * 8);
        const float4 f1 = *(const float4*)(qp + c * 32 + quad * 8 + 4);
        short8 t;
        t[0] = (short)f2bf(f0.x * 0.125f); t[1] = (short)f2bf(f0.y * 0.125f);
        t[2] = (short)f2bf(f0.z * 0.125f); t[3] = (short)f2bf(f0.w * 0.125f);
        t[4] = (short)f2bf(f1.x * 0.125f); t[5] = (short)f2bf(f1.y * 0.125f);
        t[6] = (short)f2bf(f1.z * 0.125f); t[7] = (short)f2bf(f1.w * 0.125f);
        qf[c] = t;
    }
    f32x4 acc[4];
    #pragma unroll
    for (int dt = 0; dt < 4; ++dt) acc[dt] = (f32x4){0.f, 0.f, 0.f, 0.f};
    float m_i[4] = {-1e30f, -1e30f, -1e30f, -1e30f};
    float l_i[4] = {0.f, 0.f, 0.f, 0.f};

    const int sr = tid >> 2;
    const int sc = tid & 3;
    const size_t rowstride = (size_t)HH * DD;
    const float* kbase = K + (((size_t)b * SS) * HH + h) * DD;
    const float* vbase = V + (((size_t)b * SS) * HH + h) * DD;

    for (int kt = 0; kt < NT; ++kt) {
        const int k0 = kt * BC;
        __syncthreads();
        {
            const float* kp = kbase + (size_t)(k0 + sr) * rowstride + sc * 16;
            #pragma unroll
            for (int i = 0; i < 4; ++i) {
                const float4 f = *(const float4*)(kp + i * 4);
                ushort4_t u;
                u[0] = f2bf(f.x); u[1] = f2bf(f.y); u[2] = f2bf(f.z); u[3] = f2bf(f.w);
                *(ushort4_t*)&KsF[sr][sc * 16 + i * 4] = u;
            }
            const float* vp = vbase + (size_t)(k0 + sr) * rowstride + sc * 16;
            #pragma unroll
            for (int i = 0; i < 4; ++i) {
                const float4 f = *(const float4*)(vp + i * 4);
                const int d = sc * 16 + i * 4;
                VsF[d + 0][sr] = f2bf(f.x); VsF[d + 1][sr] = f2bf(f.y);
                VsF[d + 2][sr] = f2bf(f.z); VsF[d + 3][sr] = f2bf(f.w);
            }
            if (tid < BC) mb[tid] = M[(size_t)b * SS + k0 + tid] ? -1e30f : 0.0f;
        }
        __syncthreads();
        f32x4 s[4];
        #pragma unroll
        for (int ct = 0; ct < 4; ++ct) {
            f32x4 z = (f32x4){0.f, 0.f, 0.f, 0.f};
            const unsigned short* kr = &KsF[ct * 16 + lq][quad * 8];
            const short8 kf0 = *(const short8*)kr;
            const short8 kf1 = *(const short8*)(kr + 32);
            z = __builtin_amdgcn_mfma_f32_16x16x32_bf16(qf[0], kf0, z, 0, 0, 0);
            z = __builtin_amdgcn_mfma_f32_16x16x32_bf16(qf[1], kf1, z, 0, 0, 0);
            s[ct] = z;
        }
        #pragma unroll
        for (int ct = 0; ct < 4; ++ct) {
            const float mbias = mb[ct * 16 + lq];
            s[ct][0] += mbias; s[ct][1] += mbias; s[ct][2] += mbias; s[ct][3] += mbias;
        }
        #pragma unroll
        for (int r = 0; r < 4; ++r) {
            float mx = fmaxf(fmaxf(s[0][r], s[1][r]), fmaxf(s[2][r], s[3][r]));
            mx = fmaxf(mx, __shfl_xor(mx, 1));
            mx = fmaxf(mx, __shfl_xor(mx, 2));
            mx = fmaxf(mx, __shfl_xor(mx, 4));
            mx = fmaxf(mx, __shfl_xor(mx, 8));
            const float m_new = fmaxf(m_i[r], mx);
            const float alpha = __expf(m_i[r] - m_new);
            m_i[r] = m_new;
            float rs = 0.f;
            #pragma unroll
            for (int ct = 0; ct < 4; ++ct) {
                const float p = __expf(s[ct][r] - m_new);
                rs += p;
                PsF[wave][quad * 4 + r][ct * 16 + lq] = f2bf(p);
            }
            rs += __shfl_xor(rs, 1); rs += __shfl_xor(rs, 2);
            rs += __shfl_xor(rs, 4); rs += __shfl_xor(rs, 8);
            l_i[r] = l_i[r] * alpha + rs;
            #pragma unroll
            for (int dt = 0; dt < 4; ++dt) acc[dt][r] *= alpha;
        }
        const unsigned short* pr = &PsF[wave][lq][quad * 8];
        const short8 pf0 = *(const short8*)pr;
        const short8 pf1 = *(const short8*)(pr + 32);
        #pragma unroll
        for (int dt = 0; dt < 4; ++dt) {
            const unsigned short* vr = &VsF[dt * 16 + lq][quad * 8];
            const short8 vf0 = *(const short8*)vr;
            const short8 vf1 = *(const short8*)(vr + 32);
            acc[dt] = __builtin_amdgcn_mfma_f32_16x16x32_bf16(pf0, vf0, acc[dt], 0, 0, 0);
            acc[dt] = __builtin_amdgcn_mfma_f32_16x16x32_bf16(pf1, vf1, acc[dt], 0, 0, 0);
        }
    }
    #pragma unroll
    for (int r = 0; r < 4; ++r) {
        const float inv = 1.0f / l_i[r];
        const int row = qt * FBR + wave * 16 + quad * 4 + r;
        float* op = O + (((size_t)b * SS + row) * HH + h) * DD;
        #pragma unroll
        for (int dt = 0; dt < 4; ++dt)
            op[dt * 16 + lq] = acc[dt][r] * inv;
    }
}

extern "C" void kernel_launch(void* const* d_in, const int* in_sizes, int n_in,
                              void* d_out, int out_size, void* d_ws, size_t ws_size,
                              hipStream_t stream) {
    const float* q = (const float*)d_in[0];
    const float* k = (const float*)d_in[1];
    const float* v = (const float*)d_in[2];
    const int*   m = (const int*)d_in[3];
    float* out = (float*)d_out;

    const int nprep = BB * HH * NT;                      // 1024
    const size_t kb_bytes = (size_t)nprep * TILE_E * 2;  // 8 MB
    const size_t mc_bytes = (size_t)BB * NT * 4;         // 256 B
    const size_t need_single = 2 * kb_bytes + mc_bytes;  // 16 MB + 256 B

    if (ws_size >= need_single) {
        // Non-split path: 512 blocks = exactly 2/CU x 256 CU, one residency
        // round, no partials round-trip, no combine kernel.
        unsigned short* Kb = (unsigned short*)d_ws;
        unsigned short* Vt = (unsigned short*)((char*)d_ws + kb_bytes);
        int* mcnt = (int*)((char*)d_ws + 2 * kb_bytes);
        prep_kernel<<<nprep, 256, 0, stream>>>(k, v, m, Kb, Vt, mcnt);
        fa3_kernel<false><<<BB * HH * NQT, 256, 0, stream>>>(
            q, Kb, Vt, mcnt, out, nullptr);
    } else {
        fa_fallback<<<BB * HH * (SS / FBR), 256, 0, stream>>>(q, k, v, m, out);
    }
}